// Round 2
// baseline (10896.570 us; speedup 1.0000x reference)
//
#include <hip/hip_runtime.h>
#include <cstdint>
#include <cstddef>

typedef _Float16 f16;
typedef _Float16 f16x4 __attribute__((ext_vector_type(4)));
typedef _Float16 f16x8 __attribute__((ext_vector_type(8)));
typedef float f32x4 __attribute__((ext_vector_type(4)));

#define NBATCH 256
#define NTIME  256
#define NDIN   128
#define NHID   512
#define NGATE  1536   // 3*NHID
#define NOUT   24
#define GROUPS 8      // batch groups of 32 rows
#define SLICES 16     // col slices of 32 h-cols (96 gate rows -> 96KB LDS)

__device__ __forceinline__ float sigmoidf_(float x) { return 1.0f / (1.0f + __expf(-x)); }

// ---------------- fp32 -> fp16 (weights) ----------------
__global__ void k_f32_to_f16(const float* __restrict__ in, f16* __restrict__ out, int n) {
  int stride = gridDim.x * blockDim.x;
  for (int i = blockIdx.x * blockDim.x + threadIdx.x; i < n; i += stride)
    out[i] = (f16)in[i];
}

// ---------------- gather+convert x chunk: [B, t0:t0+Tc, 128] f32 -> [B*Tc, 128] f16 ----
__global__ void k_chunk_x(const float* __restrict__ x, f16* __restrict__ xc,
                          int t0, int tc_shift7, int tcmask, int n4) {
  int stride = gridDim.x * blockDim.x;
  for (int i = blockIdx.x * blockDim.x + threadIdx.x; i < n4; i += stride) {
    int idx = i * 4;
    int b = idx >> tc_shift7;       // idx / (Tc*128)
    int rem = idx & tcmask;         // tc*128 + d
    const float4 v = *(const float4*)(x + ((size_t)b << 15) + ((size_t)t0 << 7) + rem);
    f16x4 o = {(f16)v.x, (f16)v.y, (f16)v.z, (f16)v.w};
    *(f16x4*)(xc + idx) = o;
  }
}

// ---------------- gx = A @ W^T + b  (fp16 in, fp16 out, fp32 accum) ----------------
// A[M,K] row-major, W[NGATE,K] row-major (acts as B^T). BM=128, BN=64, 4 waves 2x2.
template <int K>
__global__ __launch_bounds__(256) void k_gemm_gx(
    const f16* __restrict__ A, const f16* __restrict__ W,
    const float* __restrict__ bias, f16* __restrict__ gx) {
  const int tid = threadIdx.x;
  const int wave = tid >> 6, lane = tid & 63;
  const int wm = wave >> 1, wn = wave & 1;
  const int m0 = blockIdx.x * 128 + wm * 64;
  const int n0 = blockIdx.y * 64 + wn * 32;
  const int lr = lane & 15;
  const int lk = (lane >> 4) * 8;

  f32x4 acc[4][2];
#pragma unroll
  for (int i = 0; i < 4; i++)
#pragma unroll
    for (int j = 0; j < 2; j++) acc[i][j] = (f32x4){0.f, 0.f, 0.f, 0.f};

  const f16* Ap = A + (size_t)(m0 + lr) * K + lk;
  const f16* Wp = W + (size_t)(n0 + lr) * K + lk;
  for (int k0 = 0; k0 < K; k0 += 32) {
    f16x8 a[4], b[2];
#pragma unroll
    for (int i = 0; i < 4; i++) a[i] = *(const f16x8*)(Ap + (size_t)(i * 16) * K + k0);
#pragma unroll
    for (int j = 0; j < 2; j++) b[j] = *(const f16x8*)(Wp + (size_t)(j * 16) * K + k0);
#pragma unroll
    for (int i = 0; i < 4; i++)
#pragma unroll
      for (int j = 0; j < 2; j++)
        acc[i][j] = __builtin_amdgcn_mfma_f32_16x16x32_f16(a[i], b[j], acc[i][j], 0, 0, 0);
  }
  // C/D: col = lane&15 (B tile), row = (lane>>4)*4 + reg (A tile)
  const int rowb = (lane >> 4) * 4;
#pragma unroll
  for (int j = 0; j < 2; j++) {
    int col = n0 + j * 16 + lr;
    float bv = bias[col];
#pragma unroll
    for (int i = 0; i < 4; i++) {
#pragma unroll
      for (int r = 0; r < 4; r++) {
        int row = m0 + i * 16 + rowb + r;
        gx[(size_t)row * NGATE + col] = (f16)(acc[i][j][r] + bv);
      }
    }
  }
}

// ---------------- GRU recurrence over one time chunk ----------------
// grid = 128 blocks (8 groups x 16 slices), 256 threads (4 waves, 2x2).
// Block: rows [b0,b0+32), h cols [c0,c0+32). w_hh slice 96x512 f16 in LDS (96KB,
// XOR-swizzled 16B chunks). Per-step 16-way sibling barrier per group (agent scope).
// h carried as split fp16 hi+lo in global ping-pong (exh/exl); state persists
// across chunk launches in buffer 0 (Tc even).
__global__ __launch_bounds__(256) void k_recur(
    const f16* __restrict__ gx, const f16* __restrict__ whh,
    const float* __restrict__ bhh, f16* __restrict__ hout,
    f16* __restrict__ exh, f16* __restrict__ exl,
    unsigned* __restrict__ cnt_base, int Tc, int bar_base, int first) {
  __shared__ f16 wlds[96 * 512];
  const int tid = threadIdx.x;
  const int g = blockIdx.x >> 4;
  const int cs = blockIdx.x & 15;
  const int b0 = g * 32, c0 = cs * 32;
  const int lane = tid & 63, wave = tid >> 6;
  const int wm = wave >> 1, wn = wave & 1;

  for (int idx = tid; idx < 96 * 64; idx += 256) {
    int lrw = idx >> 6, c = idx & 63;
    int grow = (lrw >> 5) * NHID + c0 + (lrw & 31);
    f16x8 v = *(const f16x8*)(whh + (size_t)grow * NHID + c * 8);
    *(f16x8*)(wlds + lrw * 512 + ((c ^ (lrw & 7)) << 3)) = v;
  }
  __syncthreads();

  const int jloc = wn * 16 + (lane & 15);
  const int j = c0 + jloc;
  const float bh_r = bhh[j], bh_z = bhh[NHID + j], bh_n = bhh[2 * NHID + j];
  const int rbase = (lane >> 4) * 4;
  const int lk = (lane >> 4) * 8;
  const int arow = b0 + wm * 16 + (lane & 15);
  const int rowbase = b0 + wm * 16 + rbase;
  const int swz = jloc & 7;
  const f16* wr_ = wlds + jloc * 512;
  const f16* wz_ = wlds + (32 + jloc) * 512;
  const f16* wn_ = wlds + (64 + jloc) * 512;
  unsigned* cnt = cnt_base + g * 16;  // 64B apart per group

  float hold[4];
  if (first) {
#pragma unroll
    for (int r = 0; r < 4; r++) hold[r] = 0.f;
  } else {
#pragma unroll
    for (int r = 0; r < 4; r++) {
      size_t o = (size_t)(rowbase + r) * NHID + j;
      hold[r] = (float)exh[o] + (float)exl[o];
    }
  }

  int cur = 0;
  for (int t = 0; t < Tc; t++) {
    f32x4 ar = {0.f, 0.f, 0.f, 0.f}, az = {0.f, 0.f, 0.f, 0.f}, an = {0.f, 0.f, 0.f, 0.f};
    if (t > 0 || !first) {
      const f16* hh = exh + (size_t)cur * (NBATCH * NHID) + (size_t)arow * NHID;
      const f16* hl = exl + (size_t)cur * (NBATCH * NHID) + (size_t)arow * NHID;
#pragma unroll
      for (int k0 = 0; k0 < NHID; k0 += 32) {
        f16x8 ahi = *(const f16x8*)(hh + k0 + lk);
        f16x8 alo = *(const f16x8*)(hl + k0 + lk);
        int co = (((k0 >> 3) + (lane >> 4)) ^ swz) << 3;
        f16x8 br = *(const f16x8*)(wr_ + co);
        f16x8 bz = *(const f16x8*)(wz_ + co);
        f16x8 bn = *(const f16x8*)(wn_ + co);
        ar = __builtin_amdgcn_mfma_f32_16x16x32_f16(ahi, br, ar, 0, 0, 0);
        az = __builtin_amdgcn_mfma_f32_16x16x32_f16(ahi, bz, az, 0, 0, 0);
        an = __builtin_amdgcn_mfma_f32_16x16x32_f16(ahi, bn, an, 0, 0, 0);
        ar = __builtin_amdgcn_mfma_f32_16x16x32_f16(alo, br, ar, 0, 0, 0);
        az = __builtin_amdgcn_mfma_f32_16x16x32_f16(alo, bz, az, 0, 0, 0);
        an = __builtin_amdgcn_mfma_f32_16x16x32_f16(alo, bn, an, 0, 0, 0);
      }
    }
    f16* hhn = exh + (size_t)(cur ^ 1) * (NBATCH * NHID);
    f16* hln = exl + (size_t)(cur ^ 1) * (NBATCH * NHID);
#pragma unroll
    for (int r = 0; r < 4; r++) {
      int row = rowbase + r;
      size_t gxoff = ((size_t)row * Tc + t) * NGATE;
      float xr = (float)gx[gxoff + j];
      float xz = (float)gx[gxoff + NHID + j];
      float xn = (float)gx[gxoff + 2 * NHID + j];
      float rg = sigmoidf_(xr + ar[r] + bh_r);
      float zg = sigmoidf_(xz + az[r] + bh_z);
      float ng = tanhf(xn + rg * (an[r] + bh_n));
      float hnew = (1.0f - zg) * ng + zg * hold[r];
      hold[r] = hnew;
      f16 hhi = (f16)hnew;
      size_t ho = (size_t)row * NHID + j;
      hhn[ho] = hhi;
      hln[ho] = (f16)(hnew - (float)hhi);
      hout[((size_t)row * Tc + t) * NHID + j] = hhi;
    }
    if (t < Tc - 1) {
      __syncthreads();
      if (tid == 0) {
        __hip_atomic_fetch_add(cnt, 1u, __ATOMIC_RELEASE, __HIP_MEMORY_SCOPE_AGENT);
        unsigned target = 16u * (unsigned)(bar_base + t + 1);
        while (__hip_atomic_load(cnt, __ATOMIC_ACQUIRE, __HIP_MEMORY_SCOPE_AGENT) < target)
          __builtin_amdgcn_s_sleep(2);
      }
      __syncthreads();
    }
    cur ^= 1;
  }
}

// ---------------- final FC: out = h2[:, Tc-1, :] @ fc_w^T + fc_b ----------------
__global__ void k_fc(const f16* __restrict__ hlast, const float* __restrict__ fcw,
                     const float* __restrict__ fcb, float* __restrict__ out, int Tc) {
  int b = blockIdx.x;
  int lane = threadIdx.x;  // 64
  __shared__ float hrow[NHID];
  for (int k = lane; k < NHID; k += 64)
    hrow[k] = (float)hlast[((size_t)b * Tc + (Tc - 1)) * NHID + k];
  __syncthreads();
  for (int o = 0; o < NOUT; o++) {
    float s = 0.f;
    for (int k = lane; k < NHID; k += 64) s += hrow[k] * fcw[o * NHID + k];
#pragma unroll
    for (int off = 32; off; off >>= 1) s += __shfl_down(s, off);
    if (lane == 0) out[b * NOUT + o] = s + fcb[o];
  }
}

extern "C" void kernel_launch(void* const* d_in, const int* in_sizes, int n_in,
                              void* d_out, int out_size, void* d_ws, size_t ws_size,
                              hipStream_t stream) {
  (void)in_sizes; (void)n_in; (void)out_size;
  const float* x = (const float*)d_in[0];
  const float* w_ih[3] = {(const float*)d_in[1], (const float*)d_in[5], (const float*)d_in[9]};
  const float* w_hh[3] = {(const float*)d_in[2], (const float*)d_in[6], (const float*)d_in[10]};
  const float* b_ih[3] = {(const float*)d_in[3], (const float*)d_in[7], (const float*)d_in[11]};
  const float* b_hh[3] = {(const float*)d_in[4], (const float*)d_in[8], (const float*)d_in[12]};
  const float* fcw = (const float*)d_in[13];
  const float* fcb = (const float*)d_in[14];

  // ---- Tc selection from ws_size ----
  const size_t per_tc = (size_t)NBATCH * NDIN * 2 + 3 * (size_t)NBATCH * NHID * 2 +
                        (size_t)NBATCH * NGATE * 2;  // 1,638,400 B
  const size_t fixed = 4096 + (size_t)NGATE * NDIN * 2 + 2 * (size_t)NGATE * NHID * 2 +
                       3 * (size_t)NGATE * NHID * 2 + 6 * (size_t)2 * NBATCH * NHID * 2;
  int Tc = 64;
  while (Tc > 8 && fixed + per_tc * (size_t)Tc > ws_size) Tc >>= 1;
  const int nc = NTIME / Tc;

  // ---- ws layout ----
  char* ws = (char*)d_ws;
  size_t off = 0;
  unsigned* cnt = (unsigned*)(ws + off); off += 4096;  // 3 layers x 8 groups x 16 uints
  f16* wih_f[3]; f16* whh_f[3];
  const int wih_sz[3] = {NGATE * NDIN, NGATE * NHID, NGATE * NHID};
  for (int l = 0; l < 3; l++) {
    wih_f[l] = (f16*)(ws + off); off += (size_t)wih_sz[l] * 2;
    whh_f[l] = (f16*)(ws + off); off += (size_t)NGATE * NHID * 2;
  }
  f16* exh[3]; f16* exl[3];
  for (int l = 0; l < 3; l++) {
    exh[l] = (f16*)(ws + off); off += (size_t)2 * NBATCH * NHID * 2;
    exl[l] = (f16*)(ws + off); off += (size_t)2 * NBATCH * NHID * 2;
  }
  f16* xchunk = (f16*)(ws + off); off += (size_t)NBATCH * Tc * NDIN * 2;
  f16* hc[3];
  for (int l = 0; l < 3; l++) { hc[l] = (f16*)(ws + off); off += (size_t)NBATCH * Tc * NHID * 2; }
  f16* gxbuf = (f16*)(ws + off); off += (size_t)NBATCH * Tc * NGATE * 2;

  hipMemsetAsync(cnt, 0, 4096, stream);

  auto conv = [&](const float* src, f16* dst, int n) {
    int blocks = (n + 1023) / 1024; if (blocks > 2048) blocks = 2048;
    k_f32_to_f16<<<dim3(blocks), dim3(256), 0, stream>>>(src, dst, n);
  };
  for (int l = 0; l < 3; l++) {
    conv(w_ih[l], wih_f[l], wih_sz[l]);
    conv(w_hh[l], whh_f[l], NGATE * NHID);
  }

  int tcshift = 7, tctmp = Tc;
  while (tctmp > 1) { tcshift++; tctmp >>= 1; }  // log2(Tc) + 7
  const int tcmask = Tc * NDIN - 1;
  const int n4 = NBATCH * Tc * NDIN / 4;
  const int mblocks = (NBATCH * Tc) / 128;

  for (int c = 0; c < nc; c++) {
    const int t0 = c * Tc;
    const int bar_base = c * (Tc - 1);
    const int first = (c == 0) ? 1 : 0;
    {
      int blocks = (n4 + 255) / 256; if (blocks > 2048) blocks = 2048;
      k_chunk_x<<<dim3(blocks), dim3(256), 0, stream>>>(x, xchunk, t0, tcshift, tcmask, n4);
    }
    // layer 0
    k_gemm_gx<NDIN><<<dim3(mblocks, 24), dim3(256), 0, stream>>>(xchunk, wih_f[0], b_ih[0], gxbuf);
    k_recur<<<dim3(GROUPS * SLICES), dim3(256), 0, stream>>>(
        gxbuf, whh_f[0], b_hh[0], hc[0], exh[0], exl[0], cnt + 0 * GROUPS * 16, Tc, bar_base, first);
    // layer 1
    k_gemm_gx<NHID><<<dim3(mblocks, 24), dim3(256), 0, stream>>>(hc[0], wih_f[1], b_ih[1], gxbuf);
    k_recur<<<dim3(GROUPS * SLICES), dim3(256), 0, stream>>>(
        gxbuf, whh_f[1], b_hh[1], hc[1], exh[1], exl[1], cnt + 1 * GROUPS * 16, Tc, bar_base, first);
    // layer 2
    k_gemm_gx<NHID><<<dim3(mblocks, 24), dim3(256), 0, stream>>>(hc[1], wih_f[2], b_ih[2], gxbuf);
    k_recur<<<dim3(GROUPS * SLICES), dim3(256), 0, stream>>>(
        gxbuf, whh_f[2], b_hh[2], hc[2], exh[2], exl[2], cnt + 2 * GROUPS * 16, Tc, bar_base, first);
  }
  k_fc<<<dim3(NBATCH), dim3(64), 0, stream>>>(hc[2], fcw, fcb, (float*)d_out, Tc);
}

// Round 3
// 9128.844 us; speedup vs baseline: 1.1936x; 1.1936x over previous
//
#include <hip/hip_runtime.h>
#include <cstdint>
#include <cstddef>

typedef _Float16 f16;
typedef _Float16 f16x4 __attribute__((ext_vector_type(4)));
typedef _Float16 f16x8 __attribute__((ext_vector_type(8)));
typedef float f32x4 __attribute__((ext_vector_type(4)));
typedef unsigned int u32;
typedef unsigned long long u64;

#define NBATCH 256
#define NTIME  256
#define NDIN   128
#define NHID   512
#define NGATE  1536   // 3*NHID
#define NOUT   24
#define GROUPS 8      // batch groups of 32 rows
#define SLICES 16     // col slices of 32 h-cols

__device__ __forceinline__ float sigmoidf_(float x) { return 1.0f / (1.0f + __expf(-x)); }

// ---------------- fp32 -> fp16 (weights) ----------------
__global__ void k_f32_to_f16(const float* __restrict__ in, f16* __restrict__ out, int n) {
  int stride = gridDim.x * blockDim.x;
  for (int i = blockIdx.x * blockDim.x + threadIdx.x; i < n; i += stride)
    out[i] = (f16)in[i];
}

// ---------------- gather+convert x chunk: [B, t0:t0+Tc, 128] f32 -> [B*Tc, 128] f16 ----
__global__ void k_chunk_x(const float* __restrict__ x, f16* __restrict__ xc,
                          int t0, int tc_shift7, int tcmask, int n4) {
  int stride = gridDim.x * blockDim.x;
  for (int i = blockIdx.x * blockDim.x + threadIdx.x; i < n4; i += stride) {
    int idx = i * 4;
    int b = idx >> tc_shift7;       // idx / (Tc*128)
    int rem = idx & tcmask;         // tc*128 + d
    const float4 v = *(const float4*)(x + ((size_t)b << 15) + ((size_t)t0 << 7) + rem);
    f16x4 o = {(f16)v.x, (f16)v.y, (f16)v.z, (f16)v.w};
    *(f16x4*)(xc + idx) = o;
  }
}

// ---------------- gx = A @ W^T + b  (fp16 in, fp16 out, fp32 accum) ----------------
template <int K>
__global__ __launch_bounds__(256) void k_gemm_gx(
    const f16* __restrict__ A, const f16* __restrict__ W,
    const float* __restrict__ bias, f16* __restrict__ gx) {
  const int tid = threadIdx.x;
  const int wave = tid >> 6, lane = tid & 63;
  const int wm = wave >> 1, wn = wave & 1;
  const int m0 = blockIdx.x * 128 + wm * 64;
  const int n0 = blockIdx.y * 64 + wn * 32;
  const int lr = lane & 15;
  const int lk = (lane >> 4) * 8;

  f32x4 acc[4][2];
#pragma unroll
  for (int i = 0; i < 4; i++)
#pragma unroll
    for (int j = 0; j < 2; j++) acc[i][j] = (f32x4){0.f, 0.f, 0.f, 0.f};

  const f16* Ap = A + (size_t)(m0 + lr) * K + lk;
  const f16* Wp = W + (size_t)(n0 + lr) * K + lk;
  for (int k0 = 0; k0 < K; k0 += 32) {
    f16x8 a[4], b[2];
#pragma unroll
    for (int i = 0; i < 4; i++) a[i] = *(const f16x8*)(Ap + (size_t)(i * 16) * K + k0);
#pragma unroll
    for (int j = 0; j < 2; j++) b[j] = *(const f16x8*)(Wp + (size_t)(j * 16) * K + k0);
#pragma unroll
    for (int i = 0; i < 4; i++)
#pragma unroll
      for (int j = 0; j < 2; j++)
        acc[i][j] = __builtin_amdgcn_mfma_f32_16x16x32_f16(a[i], b[j], acc[i][j], 0, 0, 0);
  }
  const int rowb = (lane >> 4) * 4;
#pragma unroll
  for (int j = 0; j < 2; j++) {
    int col = n0 + j * 16 + lr;
    float bv = bias[col];
#pragma unroll
    for (int i = 0; i < 4; i++) {
#pragma unroll
      for (int r = 0; r < 4; r++) {
        int row = m0 + i * 16 + rowb + r;
        gx[(size_t)row * NGATE + col] = (f16)(acc[i][j][r] + bv);
      }
    }
  }
}

// ---------------- GRU recurrence over one time chunk ----------------
// grid = 128 blocks (8 groups x 16 slices), 256 threads (4 waves, 2x2).
// h exchanged as packed (hi:f16, lo:f16) u32 via RELAXED agent-scope atomics
// (coherent at device coherence point, no wbl2/inv). Barrier: per-group
// monotonic counter, relaxed add + relaxed poll, explicit vmcnt drain.
__global__ __launch_bounds__(256) void k_recur(
    const f16* __restrict__ gx, const f16* __restrict__ whh,
    const float* __restrict__ bhh, f16* __restrict__ hout,
    u32* __restrict__ exq, unsigned* __restrict__ cnt_base,
    int Tc, int bar_base, int first) {
  __shared__ f16 wlds[96 * 512];
  const int tid = threadIdx.x;
  const int g = blockIdx.x >> 4;
  const int cs = blockIdx.x & 15;
  const int b0 = g * 32, c0 = cs * 32;
  const int lane = tid & 63, wave = tid >> 6;
  const int wm = wave >> 1, wn = wave & 1;

  for (int idx = tid; idx < 96 * 64; idx += 256) {
    int lrw = idx >> 6, c = idx & 63;
    int grow = (lrw >> 5) * NHID + c0 + (lrw & 31);
    f16x8 v = *(const f16x8*)(whh + (size_t)grow * NHID + c * 8);
    *(f16x8*)(wlds + lrw * 512 + ((c ^ (lrw & 7)) << 3)) = v;
  }
  __syncthreads();

  const int jloc = wn * 16 + (lane & 15);
  const int j = c0 + jloc;
  const float bh_r = bhh[j], bh_z = bhh[NHID + j], bh_n = bhh[2 * NHID + j];
  const int rbase = (lane >> 4) * 4;
  const int lk = (lane >> 4) * 8;
  const int arow = b0 + wm * 16 + (lane & 15);
  const int rowbase = b0 + wm * 16 + rbase;
  const int swz = jloc & 7;
  const f16* wr_ = wlds + jloc * 512;
  const f16* wz_ = wlds + (32 + jloc) * 512;
  const f16* wn_ = wlds + (64 + jloc) * 512;
  unsigned* cnt = cnt_base + g * 16;  // 64B apart per group

  union PK2 { u32 u; f16 h[2]; };
  union Q4 { u64 q; f16 h[4]; };
  union H8 { f16x8 v; f16 h[8]; };

  float hold[4];
  if (first) {
#pragma unroll
    for (int r = 0; r < 4; r++) hold[r] = 0.f;
  } else {
#pragma unroll
    for (int r = 0; r < 4; r++) {
      PK2 pk;
      pk.u = __hip_atomic_load(exq + (size_t)(rowbase + r) * NHID + j,
                               __ATOMIC_RELAXED, __HIP_MEMORY_SCOPE_AGENT);
      hold[r] = (float)pk.h[0] + (float)pk.h[1];
    }
  }

  int cur = 0;
  for (int t = 0; t < Tc; t++) {
    // prefetch gx for this step (independent of MFMA chain)
    float xr[4], xz[4], xn[4];
#pragma unroll
    for (int r = 0; r < 4; r++) {
      size_t gxoff = ((size_t)(rowbase + r) * Tc + t) * NGATE;
      xr[r] = (float)gx[gxoff + j];
      xz[r] = (float)gx[gxoff + NHID + j];
      xn[r] = (float)gx[gxoff + 2 * NHID + j];
    }
    f32x4 ar = {0.f, 0.f, 0.f, 0.f}, az = {0.f, 0.f, 0.f, 0.f}, an = {0.f, 0.f, 0.f, 0.f};
    if (t > 0 || !first) {
      u32* hq = exq + (size_t)cur * (NBATCH * NHID) + (size_t)arow * NHID;
#pragma unroll
      for (int k0 = 0; k0 < NHID; k0 += 32) {
        const int c8 = k0 + lk;
        Q4 q0, q1, q2, q3;
        q0.q = __hip_atomic_load((u64*)(hq + c8), __ATOMIC_RELAXED, __HIP_MEMORY_SCOPE_AGENT);
        q1.q = __hip_atomic_load((u64*)(hq + c8 + 2), __ATOMIC_RELAXED, __HIP_MEMORY_SCOPE_AGENT);
        q2.q = __hip_atomic_load((u64*)(hq + c8 + 4), __ATOMIC_RELAXED, __HIP_MEMORY_SCOPE_AGENT);
        q3.q = __hip_atomic_load((u64*)(hq + c8 + 6), __ATOMIC_RELAXED, __HIP_MEMORY_SCOPE_AGENT);
        H8 ahi, alo;
        ahi.v = (f16x8){q0.h[0], q0.h[2], q1.h[0], q1.h[2], q2.h[0], q2.h[2], q3.h[0], q3.h[2]};
        alo.v = (f16x8){q0.h[1], q0.h[3], q1.h[1], q1.h[3], q2.h[1], q2.h[3], q3.h[1], q3.h[3]};
        const int co = (((k0 >> 3) + (lane >> 4)) ^ swz) << 3;
        f16x8 br = *(const f16x8*)(wr_ + co);
        f16x8 bz = *(const f16x8*)(wz_ + co);
        f16x8 bn = *(const f16x8*)(wn_ + co);
        ar = __builtin_amdgcn_mfma_f32_16x16x32_f16(ahi.v, br, ar, 0, 0, 0);
        az = __builtin_amdgcn_mfma_f32_16x16x32_f16(ahi.v, bz, az, 0, 0, 0);
        an = __builtin_amdgcn_mfma_f32_16x16x32_f16(ahi.v, bn, an, 0, 0, 0);
        ar = __builtin_amdgcn_mfma_f32_16x16x32_f16(alo.v, br, ar, 0, 0, 0);
        az = __builtin_amdgcn_mfma_f32_16x16x32_f16(alo.v, bz, az, 0, 0, 0);
        an = __builtin_amdgcn_mfma_f32_16x16x32_f16(alo.v, bn, an, 0, 0, 0);
      }
    }
    u32* outq = exq + (size_t)(cur ^ 1) * (NBATCH * NHID);
#pragma unroll
    for (int r = 0; r < 4; r++) {
      int row = rowbase + r;
      float rg = sigmoidf_(xr[r] + ar[r] + bh_r);
      float zg = sigmoidf_(xz[r] + az[r] + bh_z);
      float ng = tanhf(xn[r] + rg * (an[r] + bh_n));
      float hnew = (1.0f - zg) * ng + zg * hold[r];
      hold[r] = hnew;
      PK2 pk;
      pk.h[0] = (f16)hnew;
      pk.h[1] = (f16)(hnew - (float)pk.h[0]);
      __hip_atomic_store(outq + (size_t)row * NHID + j, pk.u,
                         __ATOMIC_RELAXED, __HIP_MEMORY_SCOPE_AGENT);
      hout[((size_t)row * Tc + t) * NHID + j] = pk.h[0];
    }
    if (t < Tc - 1) {
      asm volatile("s_waitcnt vmcnt(0)" ::: "memory");  // all exchange stores ack'd
      __syncthreads();
      if (tid == 0) {
        __hip_atomic_fetch_add(cnt, 1u, __ATOMIC_RELAXED, __HIP_MEMORY_SCOPE_AGENT);
        unsigned target = 16u * (unsigned)(bar_base + t + 1);
        while (__hip_atomic_load(cnt, __ATOMIC_RELAXED, __HIP_MEMORY_SCOPE_AGENT) < target)
          __builtin_amdgcn_s_sleep(1);
      }
      __syncthreads();
      asm volatile("" ::: "memory");
    }
    cur ^= 1;
  }
}

// ---------------- final FC: out = h2[:, Tc-1, :] @ fc_w^T + fc_b ----------------
__global__ void k_fc(const f16* __restrict__ hlast, const float* __restrict__ fcw,
                     const float* __restrict__ fcb, float* __restrict__ out, int Tc) {
  int b = blockIdx.x;
  int lane = threadIdx.x;  // 64
  __shared__ float hrow[NHID];
  for (int k = lane; k < NHID; k += 64)
    hrow[k] = (float)hlast[((size_t)b * Tc + (Tc - 1)) * NHID + k];
  __syncthreads();
  for (int o = 0; o < NOUT; o++) {
    float s = 0.f;
    for (int k = lane; k < NHID; k += 64) s += hrow[k] * fcw[o * NHID + k];
#pragma unroll
    for (int off = 32; off; off >>= 1) s += __shfl_down(s, off);
    if (lane == 0) out[b * NOUT + o] = s + fcb[o];
  }
}

extern "C" void kernel_launch(void* const* d_in, const int* in_sizes, int n_in,
                              void* d_out, int out_size, void* d_ws, size_t ws_size,
                              hipStream_t stream) {
  (void)in_sizes; (void)n_in; (void)out_size;
  const float* x = (const float*)d_in[0];
  const float* w_ih[3] = {(const float*)d_in[1], (const float*)d_in[5], (const float*)d_in[9]};
  const float* w_hh[3] = {(const float*)d_in[2], (const float*)d_in[6], (const float*)d_in[10]};
  const float* b_ih[3] = {(const float*)d_in[3], (const float*)d_in[7], (const float*)d_in[11]};
  const float* b_hh[3] = {(const float*)d_in[4], (const float*)d_in[8], (const float*)d_in[12]};
  const float* fcw = (const float*)d_in[13];
  const float* fcb = (const float*)d_in[14];

  // ---- Tc selection from ws_size ----
  const size_t per_tc = (size_t)NBATCH * NDIN * 2 + 3 * (size_t)NBATCH * NHID * 2 +
                        (size_t)NBATCH * NGATE * 2;  // 1,638,400 B
  const size_t fixed = 4096 + (size_t)NGATE * NDIN * 2 + 5 * (size_t)NGATE * NHID * 2 +
                       3 * (size_t)2 * NBATCH * NHID * 4;
  int Tc = 64;
  while (Tc > 8 && fixed + per_tc * (size_t)Tc > ws_size) Tc >>= 1;
  const int nc = NTIME / Tc;

  // ---- ws layout ----
  char* ws = (char*)d_ws;
  size_t off = 0;
  unsigned* cnt = (unsigned*)(ws + off); off += 4096;  // 3 layers x 8 groups x 16 uints
  f16* wih_f[3]; f16* whh_f[3];
  const int wih_sz[3] = {NGATE * NDIN, NGATE * NHID, NGATE * NHID};
  for (int l = 0; l < 3; l++) {
    wih_f[l] = (f16*)(ws + off); off += (size_t)wih_sz[l] * 2;
    whh_f[l] = (f16*)(ws + off); off += (size_t)NGATE * NHID * 2;
  }
  u32* exq[3];
  for (int l = 0; l < 3; l++) {
    exq[l] = (u32*)(ws + off); off += (size_t)2 * NBATCH * NHID * 4;
  }
  f16* xchunk = (f16*)(ws + off); off += (size_t)NBATCH * Tc * NDIN * 2;
  f16* hc[3];
  for (int l = 0; l < 3; l++) { hc[l] = (f16*)(ws + off); off += (size_t)NBATCH * Tc * NHID * 2; }
  f16* gxbuf = (f16*)(ws + off); off += (size_t)NBATCH * Tc * NGATE * 2;

  hipMemsetAsync(cnt, 0, 4096, stream);

  auto conv = [&](const float* src, f16* dst, int n) {
    int blocks = (n + 1023) / 1024; if (blocks > 2048) blocks = 2048;
    k_f32_to_f16<<<dim3(blocks), dim3(256), 0, stream>>>(src, dst, n);
  };
  for (int l = 0; l < 3; l++) {
    conv(w_ih[l], wih_f[l], wih_sz[l]);
    conv(w_hh[l], whh_f[l], NGATE * NHID);
  }

  int tcshift = 7, tctmp = Tc;
  while (tctmp > 1) { tcshift++; tctmp >>= 1; }  // log2(Tc) + 7
  const int tcmask = Tc * NDIN - 1;
  const int n4 = NBATCH * Tc * NDIN / 4;
  const int mblocks = (NBATCH * Tc) / 128;

  for (int c = 0; c < nc; c++) {
    const int t0 = c * Tc;
    const int bar_base = c * (Tc - 1);
    const int first = (c == 0) ? 1 : 0;
    {
      int blocks = (n4 + 255) / 256; if (blocks > 2048) blocks = 2048;
      k_chunk_x<<<dim3(blocks), dim3(256), 0, stream>>>(x, xchunk, t0, tcshift, tcmask, n4);
    }
    k_gemm_gx<NDIN><<<dim3(mblocks, 24), dim3(256), 0, stream>>>(xchunk, wih_f[0], b_ih[0], gxbuf);
    k_recur<<<dim3(GROUPS * SLICES), dim3(256), 0, stream>>>(
        gxbuf, whh_f[0], b_hh[0], hc[0], exq[0], cnt + 0 * GROUPS * 16, Tc, bar_base, first);
    k_gemm_gx<NHID><<<dim3(mblocks, 24), dim3(256), 0, stream>>>(hc[0], wih_f[1], b_ih[1], gxbuf);
    k_recur<<<dim3(GROUPS * SLICES), dim3(256), 0, stream>>>(
        gxbuf, whh_f[1], b_hh[1], hc[1], exq[1], cnt + 1 * GROUPS * 16, Tc, bar_base, first);
    k_gemm_gx<NHID><<<dim3(mblocks, 24), dim3(256), 0, stream>>>(hc[1], wih_f[2], b_ih[2], gxbuf);
    k_recur<<<dim3(GROUPS * SLICES), dim3(256), 0, stream>>>(
        gxbuf, whh_f[2], b_hh[2], hc[2], exq[2], cnt + 2 * GROUPS * 16, Tc, bar_base, first);
  }
  k_fc<<<dim3(NBATCH), dim3(64), 0, stream>>>(hc[2], fcw, fcb, (float*)d_out, Tc);
}

// Round 4
// 8820.353 us; speedup vs baseline: 1.2354x; 1.0350x over previous
//
#include <hip/hip_runtime.h>
#include <cstdint>
#include <cstddef>

typedef _Float16 f16;
typedef _Float16 f16x4 __attribute__((ext_vector_type(4)));
typedef _Float16 f16x8 __attribute__((ext_vector_type(8)));
typedef float f32x4 __attribute__((ext_vector_type(4)));
typedef unsigned int u32;
typedef unsigned long long u64;

#define NBATCH 256
#define NTIME  256
#define NDIN   128
#define NHID   512
#define NGATE  1536   // 3*NHID
#define NOUT   24
#define GROUPS 8      // batch groups of 32 rows
#define SLICES 16     // col slices of 32 h-cols

__device__ __forceinline__ float fsig(float x) {
  float e = __expf(-x);
  return __fdividef(1.0f, 1.0f + e);
}
__device__ __forceinline__ float ftanh(float x) {
  float ax = __builtin_fabsf(x);
  float e = __expf(-2.0f * ax);
  float t = __fdividef(1.0f - e, 1.0f + e);
  return __builtin_copysignf(t, x);
}

// ---------------- fp32 -> fp16 (weights) ----------------
__global__ void k_f32_to_f16(const float* __restrict__ in, f16* __restrict__ out, int n) {
  int stride = gridDim.x * blockDim.x;
  for (int i = blockIdx.x * blockDim.x + threadIdx.x; i < n; i += stride)
    out[i] = (f16)in[i];
}

// ---------------- gather+convert x chunk: [B, t0:t0+Tc, 128] f32 -> [B*Tc, 128] f16 ----
__global__ void k_chunk_x(const float* __restrict__ x, f16* __restrict__ xc,
                          int t0, int tc_shift7, int tcmask, int n4) {
  int stride = gridDim.x * blockDim.x;
  for (int i = blockIdx.x * blockDim.x + threadIdx.x; i < n4; i += stride) {
    int idx = i * 4;
    int b = idx >> tc_shift7;       // idx / (Tc*128)
    int rem = idx & tcmask;         // tc*128 + d
    const float4 v = *(const float4*)(x + ((size_t)b << 15) + ((size_t)t0 << 7) + rem);
    f16x4 o = {(f16)v.x, (f16)v.y, (f16)v.z, (f16)v.w};
    *(f16x4*)(xc + idx) = o;
  }
}

// ---------------- gx = A @ W^T + b  (fp16 in, fp16 out, fp32 accum) ----------------
template <int K>
__global__ __launch_bounds__(256) void k_gemm_gx(
    const f16* __restrict__ A, const f16* __restrict__ W,
    const float* __restrict__ bias, f16* __restrict__ gx) {
  const int tid = threadIdx.x;
  const int wave = tid >> 6, lane = tid & 63;
  const int wm = wave >> 1, wn = wave & 1;
  const int m0 = blockIdx.x * 128 + wm * 64;
  const int n0 = blockIdx.y * 64 + wn * 32;
  const int lr = lane & 15;
  const int lk = (lane >> 4) * 8;

  f32x4 acc[4][2];
#pragma unroll
  for (int i = 0; i < 4; i++)
#pragma unroll
    for (int j = 0; j < 2; j++) acc[i][j] = (f32x4){0.f, 0.f, 0.f, 0.f};

  const f16* Ap = A + (size_t)(m0 + lr) * K + lk;
  const f16* Wp = W + (size_t)(n0 + lr) * K + lk;
  for (int k0 = 0; k0 < K; k0 += 32) {
    f16x8 a[4], b[2];
#pragma unroll
    for (int i = 0; i < 4; i++) a[i] = *(const f16x8*)(Ap + (size_t)(i * 16) * K + k0);
#pragma unroll
    for (int j = 0; j < 2; j++) b[j] = *(const f16x8*)(Wp + (size_t)(j * 16) * K + k0);
#pragma unroll
    for (int i = 0; i < 4; i++)
#pragma unroll
      for (int j = 0; j < 2; j++)
        acc[i][j] = __builtin_amdgcn_mfma_f32_16x16x32_f16(a[i], b[j], acc[i][j], 0, 0, 0);
  }
  const int rowb = (lane >> 4) * 4;
#pragma unroll
  for (int j = 0; j < 2; j++) {
    int col = n0 + j * 16 + lr;
    float bv = bias[col];
#pragma unroll
    for (int i = 0; i < 4; i++) {
#pragma unroll
      for (int r = 0; r < 4; r++) {
        int row = m0 + i * 16 + rowb + r;
        gx[(size_t)row * NGATE + col] = (f16)(acc[i][j][r] + bv);
      }
    }
  }
}

// ---------------- GRU recurrence over one time chunk ----------------
// grid = 128 blocks (8 groups x 16 slices), 256 threads (4 waves, 2x2).
// Barrier: per-block flag cacheline (no RMW); all waves poll 16 flags with one
// vector load + __all, then proceed (no trailing syncthreads). gx for the next
// step is prefetched into registers before signaling.
__global__ __launch_bounds__(256) void k_recur(
    const f16* __restrict__ gx, const f16* __restrict__ whh,
    const float* __restrict__ bhh, f16* __restrict__ hout,
    u32* __restrict__ exq, u32* __restrict__ fl,
    int Tc, int bar_base, int first) {
  __shared__ f16 wlds[96 * 512];
  const int tid = threadIdx.x;
  const int g = blockIdx.x >> 4;
  const int cs = blockIdx.x & 15;
  const int b0 = g * 32, c0 = cs * 32;
  const int lane = tid & 63, wave = tid >> 6;
  const int wm = wave >> 1, wn = wave & 1;

  for (int idx = tid; idx < 96 * 64; idx += 256) {
    int lrw = idx >> 6, c = idx & 63;
    int grow = (lrw >> 5) * NHID + c0 + (lrw & 31);
    f16x8 v = *(const f16x8*)(whh + (size_t)grow * NHID + c * 8);
    *(f16x8*)(wlds + lrw * 512 + ((c ^ (lrw & 7)) << 3)) = v;
  }
  __syncthreads();

  const int jloc = wn * 16 + (lane & 15);
  const int j = c0 + jloc;
  const float bh_r = bhh[j], bh_z = bhh[NHID + j], bh_n = bhh[2 * NHID + j];
  const int rbase = (lane >> 4) * 4;
  const int lk = (lane >> 4) * 8;
  const int arow = b0 + wm * 16 + (lane & 15);
  const int rowbase = b0 + wm * 16 + rbase;
  const int swz = jloc & 7;
  const f16* wr_ = wlds + jloc * 512;
  const f16* wz_ = wlds + (32 + jloc) * 512;
  const f16* wn_ = wlds + (64 + jloc) * 512;
  u32* myflag = fl + ((g * 16 + cs) << 4);       // one 64B line per block
  u32* gflags = fl + ((g * 16) << 4);
  const int pl = lane & 15;

  union PK2 { u32 u; f16 h[2]; };
  union Q4 { u64 q; f16 h[4]; };
  union H8 { f16x8 v; f16 h[8]; };

  float hold[4];
  if (first) {
#pragma unroll
    for (int r = 0; r < 4; r++) hold[r] = 0.f;
  } else {
#pragma unroll
    for (int r = 0; r < 4; r++) {
      PK2 pk;
      pk.u = __hip_atomic_load(exq + (size_t)(rowbase + r) * NHID + j,
                               __ATOMIC_RELAXED, __HIP_MEMORY_SCOPE_AGENT);
      hold[r] = (float)pk.h[0] + (float)pk.h[1];
    }
  }

  // prefetch gx for t=0
  float xr[4], xz[4], xn[4];
#pragma unroll
  for (int r = 0; r < 4; r++) {
    size_t gxoff = ((size_t)(rowbase + r) * Tc) * NGATE;
    xr[r] = (float)gx[gxoff + j];
    xz[r] = (float)gx[gxoff + NHID + j];
    xn[r] = (float)gx[gxoff + 2 * NHID + j];
  }

  int cur = 0;
  for (int t = 0; t < Tc; t++) {
    f32x4 ar = {0.f, 0.f, 0.f, 0.f}, az = {0.f, 0.f, 0.f, 0.f}, an = {0.f, 0.f, 0.f, 0.f};
    if (t > 0 || !first) {
      u32* hq = exq + (size_t)cur * (NBATCH * NHID) + (size_t)arow * NHID;
#pragma unroll
      for (int k0 = 0; k0 < NHID; k0 += 32) {
        const int c8 = k0 + lk;
        Q4 q0, q1, q2, q3;
        q0.q = __hip_atomic_load((u64*)(hq + c8), __ATOMIC_RELAXED, __HIP_MEMORY_SCOPE_AGENT);
        q1.q = __hip_atomic_load((u64*)(hq + c8 + 2), __ATOMIC_RELAXED, __HIP_MEMORY_SCOPE_AGENT);
        q2.q = __hip_atomic_load((u64*)(hq + c8 + 4), __ATOMIC_RELAXED, __HIP_MEMORY_SCOPE_AGENT);
        q3.q = __hip_atomic_load((u64*)(hq + c8 + 6), __ATOMIC_RELAXED, __HIP_MEMORY_SCOPE_AGENT);
        H8 ahi, alo;
        ahi.v = (f16x8){q0.h[0], q0.h[2], q1.h[0], q1.h[2], q2.h[0], q2.h[2], q3.h[0], q3.h[2]};
        alo.v = (f16x8){q0.h[1], q0.h[3], q1.h[1], q1.h[3], q2.h[1], q2.h[3], q3.h[1], q3.h[3]};
        const int co = (((k0 >> 3) + (lane >> 4)) ^ swz) << 3;
        f16x8 br = *(const f16x8*)(wr_ + co);
        f16x8 bz = *(const f16x8*)(wz_ + co);
        f16x8 bn = *(const f16x8*)(wn_ + co);
        ar = __builtin_amdgcn_mfma_f32_16x16x32_f16(ahi.v, br, ar, 0, 0, 0);
        az = __builtin_amdgcn_mfma_f32_16x16x32_f16(ahi.v, bz, az, 0, 0, 0);
        an = __builtin_amdgcn_mfma_f32_16x16x32_f16(ahi.v, bn, an, 0, 0, 0);
        ar = __builtin_amdgcn_mfma_f32_16x16x32_f16(alo.v, br, ar, 0, 0, 0);
        az = __builtin_amdgcn_mfma_f32_16x16x32_f16(alo.v, bz, az, 0, 0, 0);
        an = __builtin_amdgcn_mfma_f32_16x16x32_f16(alo.v, bn, an, 0, 0, 0);
      }
    }
    u32* outq = exq + (size_t)(cur ^ 1) * (NBATCH * NHID);
    float nxr[4], nxz[4], nxn[4];
    const int tn = (t + 1 < Tc) ? t + 1 : t;
#pragma unroll
    for (int r = 0; r < 4; r++) {
      // prefetch next step's gx (independent; overlaps gates + barrier)
      size_t gxo = ((size_t)(rowbase + r) * Tc + tn) * NGATE;
      nxr[r] = (float)gx[gxo + j];
      nxz[r] = (float)gx[gxo + NHID + j];
      nxn[r] = (float)gx[gxo + 2 * NHID + j];
      int row = rowbase + r;
      float rg = fsig(xr[r] + ar[r] + bh_r);
      float zg = fsig(xz[r] + az[r] + bh_z);
      float ng = ftanh(xn[r] + rg * (an[r] + bh_n));
      float hnew = ng + zg * (hold[r] - ng);
      hold[r] = hnew;
      PK2 pk;
      pk.h[0] = (f16)hnew;
      pk.h[1] = (f16)(hnew - (float)pk.h[0]);
      __hip_atomic_store(outq + (size_t)row * NHID + j, pk.u,
                         __ATOMIC_RELAXED, __HIP_MEMORY_SCOPE_AGENT);
      hout[((size_t)row * Tc + t) * NHID + j] = pk.h[0];
    }
#pragma unroll
    for (int r = 0; r < 4; r++) { xr[r] = nxr[r]; xz[r] = nxz[r]; xn[r] = nxn[r]; }
    if (t < Tc - 1) {
      asm volatile("s_waitcnt vmcnt(0)" ::: "memory");  // h stores ack'd at fabric
      __syncthreads();                                   // all 4 waves drained
      if (tid == 0)
        __hip_atomic_store(myflag, (u32)(bar_base + t + 1),
                           __ATOMIC_RELAXED, __HIP_MEMORY_SCOPE_AGENT);
      const u32 target = (u32)(bar_base + t + 1);
      for (;;) {
        u32 v = __hip_atomic_load(gflags + (pl << 4),
                                  __ATOMIC_RELAXED, __HIP_MEMORY_SCOPE_AGENT);
        if (__all((lane < 16) ? (v >= target) : 1)) break;
        __builtin_amdgcn_s_sleep(1);
      }
      asm volatile("" ::: "memory");
    }
    cur ^= 1;
  }
}

// ---------------- final FC: out = h2[:, Tc-1, :] @ fc_w^T + fc_b ----------------
__global__ void k_fc(const f16* __restrict__ hlast, const float* __restrict__ fcw,
                     const float* __restrict__ fcb, float* __restrict__ out, int Tc) {
  int b = blockIdx.x;
  int lane = threadIdx.x;  // 64
  __shared__ float hrow[NHID];
  for (int k = lane; k < NHID; k += 64)
    hrow[k] = (float)hlast[((size_t)b * Tc + (Tc - 1)) * NHID + k];
  __syncthreads();
  for (int o = 0; o < NOUT; o++) {
    float s = 0.f;
    for (int k = lane; k < NHID; k += 64) s += hrow[k] * fcw[o * NHID + k];
#pragma unroll
    for (int off = 32; off; off >>= 1) s += __shfl_down(s, off);
    if (lane == 0) out[b * NOUT + o] = s + fcb[o];
  }
}

extern "C" void kernel_launch(void* const* d_in, const int* in_sizes, int n_in,
                              void* d_out, int out_size, void* d_ws, size_t ws_size,
                              hipStream_t stream) {
  (void)in_sizes; (void)n_in; (void)out_size;
  const float* x = (const float*)d_in[0];
  const float* w_ih[3] = {(const float*)d_in[1], (const float*)d_in[5], (const float*)d_in[9]};
  const float* w_hh[3] = {(const float*)d_in[2], (const float*)d_in[6], (const float*)d_in[10]};
  const float* b_ih[3] = {(const float*)d_in[3], (const float*)d_in[7], (const float*)d_in[11]};
  const float* b_hh[3] = {(const float*)d_in[4], (const float*)d_in[8], (const float*)d_in[12]};
  const float* fcw = (const float*)d_in[13];
  const float* fcb = (const float*)d_in[14];

  // ---- Tc selection from ws_size ----
  const size_t per_tc = (size_t)NBATCH * NDIN * 2 + 3 * (size_t)NBATCH * NHID * 2 +
                        (size_t)NBATCH * NGATE * 2;  // 1,638,400 B
  const size_t fixed = 32768 + (size_t)NGATE * NDIN * 2 + 5 * (size_t)NGATE * NHID * 2 +
                       3 * (size_t)2 * NBATCH * NHID * 4;
  int Tc = 64;
  while (Tc > 8 && fixed + per_tc * (size_t)Tc > ws_size) Tc >>= 1;
  const int nc = NTIME / Tc;

  // ---- ws layout ----
  char* ws = (char*)d_ws;
  size_t off = 0;
  u32* flags = (u32*)(ws + off); off += 32768;  // 3 layers x 8 groups x 16 slices x 64B
  f16* wih_f[3]; f16* whh_f[3];
  const int wih_sz[3] = {NGATE * NDIN, NGATE * NHID, NGATE * NHID};
  for (int l = 0; l < 3; l++) {
    wih_f[l] = (f16*)(ws + off); off += (size_t)wih_sz[l] * 2;
    whh_f[l] = (f16*)(ws + off); off += (size_t)NGATE * NHID * 2;
  }
  u32* exq[3];
  for (int l = 0; l < 3; l++) {
    exq[l] = (u32*)(ws + off); off += (size_t)2 * NBATCH * NHID * 4;
  }
  f16* xchunk = (f16*)(ws + off); off += (size_t)NBATCH * Tc * NDIN * 2;
  f16* hc[3];
  for (int l = 0; l < 3; l++) { hc[l] = (f16*)(ws + off); off += (size_t)NBATCH * Tc * NHID * 2; }
  f16* gxbuf = (f16*)(ws + off); off += (size_t)NBATCH * Tc * NGATE * 2;

  hipMemsetAsync(flags, 0, 32768, stream);

  auto conv = [&](const float* src, f16* dst, int n) {
    int blocks = (n + 1023) / 1024; if (blocks > 2048) blocks = 2048;
    k_f32_to_f16<<<dim3(blocks), dim3(256), 0, stream>>>(src, dst, n);
  };
  for (int l = 0; l < 3; l++) {
    conv(w_ih[l], wih_f[l], wih_sz[l]);
    conv(w_hh[l], whh_f[l], NGATE * NHID);
  }

  int tcshift = 7, tctmp = Tc;
  while (tctmp > 1) { tcshift++; tctmp >>= 1; }  // log2(Tc) + 7
  const int tcmask = Tc * NDIN - 1;
  const int n4 = NBATCH * Tc * NDIN / 4;
  const int mblocks = (NBATCH * Tc) / 128;

  for (int c = 0; c < nc; c++) {
    const int t0 = c * Tc;
    const int bar_base = c * (Tc - 1);
    const int first = (c == 0) ? 1 : 0;
    {
      int blocks = (n4 + 255) / 256; if (blocks > 2048) blocks = 2048;
      k_chunk_x<<<dim3(blocks), dim3(256), 0, stream>>>(x, xchunk, t0, tcshift, tcmask, n4);
    }
    k_gemm_gx<NDIN><<<dim3(mblocks, 24), dim3(256), 0, stream>>>(xchunk, wih_f[0], b_ih[0], gxbuf);
    k_recur<<<dim3(GROUPS * SLICES), dim3(256), 0, stream>>>(
        gxbuf, whh_f[0], b_hh[0], hc[0], exq[0], flags + 0 * GROUPS * SLICES * 16,
        Tc, bar_base, first);
    k_gemm_gx<NHID><<<dim3(mblocks, 24), dim3(256), 0, stream>>>(hc[0], wih_f[1], b_ih[1], gxbuf);
    k_recur<<<dim3(GROUPS * SLICES), dim3(256), 0, stream>>>(
        gxbuf, whh_f[1], b_hh[1], hc[1], exq[1], flags + 1 * GROUPS * SLICES * 16,
        Tc, bar_base, first);
    k_gemm_gx<NHID><<<dim3(mblocks, 24), dim3(256), 0, stream>>>(hc[1], wih_f[2], b_ih[2], gxbuf);
    k_recur<<<dim3(GROUPS * SLICES), dim3(256), 0, stream>>>(
        gxbuf, whh_f[2], b_hh[2], hc[2], exq[2], flags + 2 * GROUPS * SLICES * 16,
        Tc, bar_base, first);
  }
  k_fc<<<dim3(NBATCH), dim3(64), 0, stream>>>(hc[2], fcw, fcb, (float*)d_out, Tc);
}

// Round 5
// 8508.957 us; speedup vs baseline: 1.2806x; 1.0366x over previous
//
#include <hip/hip_runtime.h>
#include <cstdint>
#include <cstddef>

typedef _Float16 f16;
typedef _Float16 f16x4 __attribute__((ext_vector_type(4)));
typedef _Float16 f16x8 __attribute__((ext_vector_type(8)));
typedef float f32x4 __attribute__((ext_vector_type(4)));
typedef unsigned int u32;
typedef unsigned long long u64;

#define NBATCH 256
#define NTIME  256
#define NDIN   128
#define NHID   512
#define NGATE  1536   // 3*NHID
#define NOUT   24
#define GROUPS 8      // batch groups of 32 rows
#define SLICES 16     // col slices of 32 h-cols

__device__ __forceinline__ float fsig(float x) {
  float e = __expf(-x);
  return __fdividef(1.0f, 1.0f + e);
}
__device__ __forceinline__ float ftanh(float x) {
  float ax = __builtin_fabsf(x);
  float e = __expf(-2.0f * ax);
  float t = __fdividef(1.0f - e, 1.0f + e);
  return __builtin_copysignf(t, x);
}

// ---------------- fp32 -> fp16 (weights) ----------------
__global__ void k_f32_to_f16(const float* __restrict__ in, f16* __restrict__ out, int n) {
  int stride = gridDim.x * blockDim.x;
  for (int i = blockIdx.x * blockDim.x + threadIdx.x; i < n; i += stride)
    out[i] = (f16)in[i];
}

// ---------------- gather+convert x chunk: [B, t0:t0+Tc, 128] f32 -> [B*Tc, 128] f16 ----
__global__ void k_chunk_x(const float* __restrict__ x, f16* __restrict__ xc,
                          int t0, int tc_shift7, int tcmask, int n4) {
  int stride = gridDim.x * blockDim.x;
  for (int i = blockIdx.x * blockDim.x + threadIdx.x; i < n4; i += stride) {
    int idx = i * 4;
    int b = idx >> tc_shift7;       // idx / (Tc*128)
    int rem = idx & tcmask;         // tc*128 + d
    const float4 v = *(const float4*)(x + ((size_t)b << 15) + ((size_t)t0 << 7) + rem);
    f16x4 o = {(f16)v.x, (f16)v.y, (f16)v.z, (f16)v.w};
    *(f16x4*)(xc + idx) = o;
  }
}

// ---------------- gx = A @ W^T + b  (fp16 in, fp16 out, fp32 accum) ----------------
template <int K>
__global__ __launch_bounds__(256) void k_gemm_gx(
    const f16* __restrict__ A, const f16* __restrict__ W,
    const float* __restrict__ bias, f16* __restrict__ gx) {
  const int tid = threadIdx.x;
  const int wave = tid >> 6, lane = tid & 63;
  const int wm = wave >> 1, wn = wave & 1;
  const int m0 = blockIdx.x * 128 + wm * 64;
  const int n0 = blockIdx.y * 64 + wn * 32;
  const int lr = lane & 15;
  const int lk = (lane >> 4) * 8;

  f32x4 acc[4][2];
#pragma unroll
  for (int i = 0; i < 4; i++)
#pragma unroll
    for (int j = 0; j < 2; j++) acc[i][j] = (f32x4){0.f, 0.f, 0.f, 0.f};

  const f16* Ap = A + (size_t)(m0 + lr) * K + lk;
  const f16* Wp = W + (size_t)(n0 + lr) * K + lk;
  for (int k0 = 0; k0 < K; k0 += 32) {
    f16x8 a[4], b[2];
#pragma unroll
    for (int i = 0; i < 4; i++) a[i] = *(const f16x8*)(Ap + (size_t)(i * 16) * K + k0);
#pragma unroll
    for (int j = 0; j < 2; j++) b[j] = *(const f16x8*)(Wp + (size_t)(j * 16) * K + k0);
#pragma unroll
    for (int i = 0; i < 4; i++)
#pragma unroll
      for (int j = 0; j < 2; j++)
        acc[i][j] = __builtin_amdgcn_mfma_f32_16x16x32_f16(a[i], b[j], acc[i][j], 0, 0, 0);
  }
  const int rowb = (lane >> 4) * 4;
#pragma unroll
  for (int j = 0; j < 2; j++) {
    int col = n0 + j * 16 + lr;
    float bv = bias[col];
#pragma unroll
    for (int i = 0; i < 4; i++) {
#pragma unroll
      for (int r = 0; r < 4; r++) {
        int row = m0 + i * 16 + rowb + r;
        gx[(size_t)row * NGATE + col] = (f16)(acc[i][j][r] + bv);
      }
    }
  }
}

// ---------------- GRU recurrence over one time chunk ----------------
// grid = 128 blocks (8 groups x 16 slices), 256 threads (4 waves, 2x2).
// Weights: one-time LDS stage -> hoisted into 192 VGPRs of B-fragments per
// wave; steady-state loop does NO LDS traffic. Step tail: exchange stores ->
// vmcnt(0) -> syncthreads -> flag -> (hout + next-gx prefetch hidden under
// poll) -> poll 16 flags.
__global__ __launch_bounds__(256, 1) void k_recur(
    const f16* __restrict__ gx, const f16* __restrict__ whh,
    const float* __restrict__ bhh, f16* __restrict__ hout,
    u32* __restrict__ exq, u32* __restrict__ fl,
    int Tc, int bar_base, int first) {
  __shared__ f16 wlds[96 * 512];
  const int tid = threadIdx.x;
  const int g = blockIdx.x >> 4;
  const int cs = blockIdx.x & 15;
  const int b0 = g * 32, c0 = cs * 32;
  const int lane = tid & 63, wave = tid >> 6;
  const int wm = wave >> 1, wn = wave & 1;

  for (int idx = tid; idx < 96 * 64; idx += 256) {
    int lrw = idx >> 6, c = idx & 63;
    int grow = (lrw >> 5) * NHID + c0 + (lrw & 31);
    f16x8 v = *(const f16x8*)(whh + (size_t)grow * NHID + c * 8);
    *(f16x8*)(wlds + lrw * 512 + ((c ^ (lrw & 7)) << 3)) = v;
  }
  __syncthreads();

  const int jloc = wn * 16 + (lane & 15);
  const int j = c0 + jloc;
  const float bh_r = bhh[j], bh_z = bhh[NHID + j], bh_n = bhh[2 * NHID + j];
  const int rbase = (lane >> 4) * 4;
  const int lk = (lane >> 4) * 8;
  const int arow = b0 + wm * 16 + (lane & 15);
  const int rowbase = b0 + wm * 16 + rbase;
  const int swz = jloc & 7;
  const f16* wr_ = wlds + jloc * 512;
  const f16* wz_ = wlds + (32 + jloc) * 512;
  const f16* wn_ = wlds + (64 + jloc) * 512;
  u32* myflag = fl + ((g * 16 + cs) << 4);       // one 64B line per block
  u32* gflags = fl + ((g * 16) << 4);
  const int pl = lane & 15;

  // hoist all B-fragments into registers (one-time; 192 VGPRs)
  f16x8 br_[16], bz_[16], bn_[16];
#pragma unroll
  for (int kk = 0; kk < 16; kk++) {
    const int co = (((kk * 4 + (lane >> 4)) ^ swz) << 3);
    br_[kk] = *(const f16x8*)(wr_ + co);
    bz_[kk] = *(const f16x8*)(wz_ + co);
    bn_[kk] = *(const f16x8*)(wn_ + co);
  }

  union PK2 { u32 u; f16 h[2]; };
  union Q4 { u64 q; f16 h[4]; };
  union H8 { f16x8 v; f16 h[8]; };

  float hold[4];
  if (first) {
#pragma unroll
    for (int r = 0; r < 4; r++) hold[r] = 0.f;
  } else {
#pragma unroll
    for (int r = 0; r < 4; r++) {
      PK2 pk;
      pk.u = __hip_atomic_load(exq + (size_t)(rowbase + r) * NHID + j,
                               __ATOMIC_RELAXED, __HIP_MEMORY_SCOPE_AGENT);
      hold[r] = (float)pk.h[0] + (float)pk.h[1];
    }
  }

  // prefetch gx for t=0
  float xr[4], xz[4], xn[4];
#pragma unroll
  for (int r = 0; r < 4; r++) {
    size_t gxoff = ((size_t)(rowbase + r) * Tc) * NGATE;
    xr[r] = (float)gx[gxoff + j];
    xz[r] = (float)gx[gxoff + NHID + j];
    xn[r] = (float)gx[gxoff + 2 * NHID + j];
  }

  int cur = 0;
  for (int t = 0; t < Tc; t++) {
    f32x4 ar = {0.f, 0.f, 0.f, 0.f}, az = {0.f, 0.f, 0.f, 0.f}, an = {0.f, 0.f, 0.f, 0.f};
    if (t > 0 || !first) {
      u32* hq = exq + (size_t)cur * (NBATCH * NHID) + (size_t)arow * NHID;
#pragma unroll
      for (int kk = 0; kk < 16; kk++) {
        const int c8 = kk * 32 + lk;
        Q4 q0, q1, q2, q3;
        q0.q = __hip_atomic_load((u64*)(hq + c8), __ATOMIC_RELAXED, __HIP_MEMORY_SCOPE_AGENT);
        q1.q = __hip_atomic_load((u64*)(hq + c8 + 2), __ATOMIC_RELAXED, __HIP_MEMORY_SCOPE_AGENT);
        q2.q = __hip_atomic_load((u64*)(hq + c8 + 4), __ATOMIC_RELAXED, __HIP_MEMORY_SCOPE_AGENT);
        q3.q = __hip_atomic_load((u64*)(hq + c8 + 6), __ATOMIC_RELAXED, __HIP_MEMORY_SCOPE_AGENT);
        H8 ahi, alo;
        ahi.v = (f16x8){q0.h[0], q0.h[2], q1.h[0], q1.h[2], q2.h[0], q2.h[2], q3.h[0], q3.h[2]};
        alo.v = (f16x8){q0.h[1], q0.h[3], q1.h[1], q1.h[3], q2.h[1], q2.h[3], q3.h[1], q3.h[3]};
        ar = __builtin_amdgcn_mfma_f32_16x16x32_f16(ahi.v, br_[kk], ar, 0, 0, 0);
        az = __builtin_amdgcn_mfma_f32_16x16x32_f16(ahi.v, bz_[kk], az, 0, 0, 0);
        an = __builtin_amdgcn_mfma_f32_16x16x32_f16(ahi.v, bn_[kk], an, 0, 0, 0);
        ar = __builtin_amdgcn_mfma_f32_16x16x32_f16(alo.v, br_[kk], ar, 0, 0, 0);
        az = __builtin_amdgcn_mfma_f32_16x16x32_f16(alo.v, bz_[kk], az, 0, 0, 0);
        an = __builtin_amdgcn_mfma_f32_16x16x32_f16(alo.v, bn_[kk], an, 0, 0, 0);
      }
    }
    u32* outq = exq + (size_t)(cur ^ 1) * (NBATCH * NHID);
    f16 hhi_s[4];
#pragma unroll
    for (int r = 0; r < 4; r++) {
      int row = rowbase + r;
      float rg = fsig(xr[r] + ar[r] + bh_r);
      float zg = fsig(xz[r] + az[r] + bh_z);
      float ng = ftanh(xn[r] + rg * (an[r] + bh_n));
      float hnew = ng + zg * (hold[r] - ng);
      hold[r] = hnew;
      PK2 pk;
      pk.h[0] = (f16)hnew;
      pk.h[1] = (f16)(hnew - (float)pk.h[0]);
      hhi_s[r] = pk.h[0];
      __hip_atomic_store(outq + (size_t)row * NHID + j, pk.u,
                         __ATOMIC_RELAXED, __HIP_MEMORY_SCOPE_AGENT);
    }
    if (t < Tc - 1) {
      asm volatile("s_waitcnt vmcnt(0)" ::: "memory");  // exchange stores ack'd
      __syncthreads();                                   // all 4 waves drained
      if (tid == 0)
        __hip_atomic_store(myflag, (u32)(bar_base + t + 1),
                           __ATOMIC_RELAXED, __HIP_MEMORY_SCOPE_AGENT);
      // hout stores + next-step gx prefetch: latency hidden under the poll
#pragma unroll
      for (int r = 0; r < 4; r++)
        hout[((size_t)(rowbase + r) * Tc + t) * NHID + j] = hhi_s[r];
#pragma unroll
      for (int r = 0; r < 4; r++) {
        size_t gxo = ((size_t)(rowbase + r) * Tc + t + 1) * NGATE;
        xr[r] = (float)gx[gxo + j];
        xz[r] = (float)gx[gxo + NHID + j];
        xn[r] = (float)gx[gxo + 2 * NHID + j];
      }
      asm volatile("" ::: "memory");  // pin prefetch issue before the poll
      const u32 target = (u32)(bar_base + t + 1);
      for (;;) {
        u32 v = __hip_atomic_load(gflags + (pl << 4),
                                  __ATOMIC_RELAXED, __HIP_MEMORY_SCOPE_AGENT);
        if (__all(v >= target)) break;
      }
      asm volatile("" ::: "memory");
    } else {
#pragma unroll
      for (int r = 0; r < 4; r++)
        hout[((size_t)(rowbase + r) * Tc + t) * NHID + j] = hhi_s[r];
    }
    cur ^= 1;
  }
}

// ---------------- final FC: out = h2[:, Tc-1, :] @ fc_w^T + fc_b ----------------
__global__ void k_fc(const f16* __restrict__ hlast, const float* __restrict__ fcw,
                     const float* __restrict__ fcb, float* __restrict__ out, int Tc) {
  int b = blockIdx.x;
  int lane = threadIdx.x;  // 64
  __shared__ float hrow[NHID];
  for (int k = lane; k < NHID; k += 64)
    hrow[k] = (float)hlast[((size_t)b * Tc + (Tc - 1)) * NHID + k];
  __syncthreads();
  for (int o = 0; o < NOUT; o++) {
    float s = 0.f;
    for (int k = lane; k < NHID; k += 64) s += hrow[k] * fcw[o * NHID + k];
#pragma unroll
    for (int off = 32; off; off >>= 1) s += __shfl_down(s, off);
    if (lane == 0) out[b * NOUT + o] = s + fcb[o];
  }
}

extern "C" void kernel_launch(void* const* d_in, const int* in_sizes, int n_in,
                              void* d_out, int out_size, void* d_ws, size_t ws_size,
                              hipStream_t stream) {
  (void)in_sizes; (void)n_in; (void)out_size;
  const float* x = (const float*)d_in[0];
  const float* w_ih[3] = {(const float*)d_in[1], (const float*)d_in[5], (const float*)d_in[9]};
  const float* w_hh[3] = {(const float*)d_in[2], (const float*)d_in[6], (const float*)d_in[10]};
  const float* b_ih[3] = {(const float*)d_in[3], (const float*)d_in[7], (const float*)d_in[11]};
  const float* b_hh[3] = {(const float*)d_in[4], (const float*)d_in[8], (const float*)d_in[12]};
  const float* fcw = (const float*)d_in[13];
  const float* fcb = (const float*)d_in[14];

  // ---- Tc selection from ws_size ----
  const size_t per_tc = (size_t)NBATCH * NDIN * 2 + 3 * (size_t)NBATCH * NHID * 2 +
                        (size_t)NBATCH * NGATE * 2;  // 1,638,400 B
  const size_t fixed = 32768 + (size_t)NGATE * NDIN * 2 + 5 * (size_t)NGATE * NHID * 2 +
                       3 * (size_t)2 * NBATCH * NHID * 4;
  int Tc = 64;
  while (Tc > 8 && fixed + per_tc * (size_t)Tc > ws_size) Tc >>= 1;
  const int nc = NTIME / Tc;

  // ---- ws layout ----
  char* ws = (char*)d_ws;
  size_t off = 0;
  u32* flags = (u32*)(ws + off); off += 32768;  // 3 layers x 8 groups x 16 slices x 64B
  f16* wih_f[3]; f16* whh_f[3];
  const int wih_sz[3] = {NGATE * NDIN, NGATE * NHID, NGATE * NHID};
  for (int l = 0; l < 3; l++) {
    wih_f[l] = (f16*)(ws + off); off += (size_t)wih_sz[l] * 2;
    whh_f[l] = (f16*)(ws + off); off += (size_t)NGATE * NHID * 2;
  }
  u32* exq[3];
  for (int l = 0; l < 3; l++) {
    exq[l] = (u32*)(ws + off); off += (size_t)2 * NBATCH * NHID * 4;
  }
  f16* xchunk = (f16*)(ws + off); off += (size_t)NBATCH * Tc * NDIN * 2;
  f16* hc[3];
  for (int l = 0; l < 3; l++) { hc[l] = (f16*)(ws + off); off += (size_t)NBATCH * Tc * NHID * 2; }
  f16* gxbuf = (f16*)(ws + off); off += (size_t)NBATCH * Tc * NGATE * 2;

  hipMemsetAsync(flags, 0, 32768, stream);

  auto conv = [&](const float* src, f16* dst, int n) {
    int blocks = (n + 1023) / 1024; if (blocks > 2048) blocks = 2048;
    k_f32_to_f16<<<dim3(blocks), dim3(256), 0, stream>>>(src, dst, n);
  };
  for (int l = 0; l < 3; l++) {
    conv(w_ih[l], wih_f[l], wih_sz[l]);
    conv(w_hh[l], whh_f[l], NGATE * NHID);
  }

  int tcshift = 7, tctmp = Tc;
  while (tctmp > 1) { tcshift++; tctmp >>= 1; }  // log2(Tc) + 7
  const int tcmask = Tc * NDIN - 1;
  const int n4 = NBATCH * Tc * NDIN / 4;
  const int mblocks = (NBATCH * Tc) / 128;

  for (int c = 0; c < nc; c++) {
    const int t0 = c * Tc;
    const int bar_base = c * (Tc - 1);
    const int first = (c == 0) ? 1 : 0;
    {
      int blocks = (n4 + 255) / 256; if (blocks > 2048) blocks = 2048;
      k_chunk_x<<<dim3(blocks), dim3(256), 0, stream>>>(x, xchunk, t0, tcshift, tcmask, n4);
    }
    k_gemm_gx<NDIN><<<dim3(mblocks, 24), dim3(256), 0, stream>>>(xchunk, wih_f[0], b_ih[0], gxbuf);
    k_recur<<<dim3(GROUPS * SLICES), dim3(256), 0, stream>>>(
        gxbuf, whh_f[0], b_hh[0], hc[0], exq[0], flags + 0 * GROUPS * SLICES * 16,
        Tc, bar_base, first);
    k_gemm_gx<NHID><<<dim3(mblocks, 24), dim3(256), 0, stream>>>(hc[0], wih_f[1], b_ih[1], gxbuf);
    k_recur<<<dim3(GROUPS * SLICES), dim3(256), 0, stream>>>(
        gxbuf, whh_f[1], b_hh[1], hc[1], exq[1], flags + 1 * GROUPS * SLICES * 16,
        Tc, bar_base, first);
    k_gemm_gx<NHID><<<dim3(mblocks, 24), dim3(256), 0, stream>>>(hc[1], wih_f[2], b_ih[2], gxbuf);
    k_recur<<<dim3(GROUPS * SLICES), dim3(256), 0, stream>>>(
        gxbuf, whh_f[2], b_hh[2], hc[2], exq[2], flags + 2 * GROUPS * SLICES * 16,
        Tc, bar_base, first);
  }
  k_fc<<<dim3(NBATCH), dim3(64), 0, stream>>>(hc[2], fcw, fcb, (float*)d_out, Tc);
}

// Round 6
// 8169.956 us; speedup vs baseline: 1.3337x; 1.0415x over previous
//
#include <hip/hip_runtime.h>
#include <cstdint>
#include <cstddef>

typedef _Float16 f16;
typedef _Float16 f16x8 __attribute__((ext_vector_type(8)));
typedef float f32x4 __attribute__((ext_vector_type(4)));
typedef unsigned int u32;
typedef u32 u32x4 __attribute__((ext_vector_type(4)));
typedef unsigned long long u64;

#define NB 256
#define NT 256
#define ND 128
#define NH 512
#define NG 1536
#define NOUT 24

__device__ __forceinline__ float fsig(float x) {
  float e = __expf(-x);
  return __fdividef(1.0f, 1.0f + e);
}
__device__ __forceinline__ float ftanh(float x) {
  float ax = __builtin_fabsf(x);
  float e = __expf(-2.0f * ax);
  float t = __fdividef(1.0f - e, 1.0f + e);
  return __builtin_copysignf(t, x);
}

__global__ void k_f32_to_f16(const float* __restrict__ in, f16* __restrict__ out, int n) {
  int stride = gridDim.x * blockDim.x;
  for (int i = blockIdx.x * blockDim.x + threadIdx.x; i < n; i += stride)
    out[i] = (f16)in[i];
}

__device__ __forceinline__ f16x8 ld8(const f16* p) { return *(const f16x8*)p; }
__device__ __forceinline__ f16x8 ld8(const float* p) {
  float4 a = *(const float4*)p;
  float4 b = *(const float4*)(p + 4);
  f16x8 o;
  o[0] = (f16)a.x; o[1] = (f16)a.y; o[2] = (f16)a.z; o[3] = (f16)a.w;
  o[4] = (f16)b.x; o[5] = (f16)b.y; o[6] = (f16)b.z; o[7] = (f16)b.w;
  return o;
}

// ---- gx = A @ W^T + b. A rows are (b, t0+tl) pairs: M-index r -> b=r>>tsh, tl=r&mask.
template <int K, typename TA>
__global__ __launch_bounds__(256) void k_gemm(
    const TA* __restrict__ A, const f16* __restrict__ W,
    const float* __restrict__ bias, f16* __restrict__ gx, int t0, int tsh) {
  const int tid = threadIdx.x;
  const int wave = tid >> 6, lane = tid & 63;
  const int wm = wave >> 1, wn = wave & 1;
  const int m0 = blockIdx.x * 128 + wm * 64;
  const int n0 = blockIdx.y * 64 + wn * 32;
  const int lr = lane & 15;
  const int lk = (lane >> 4) * 8;
  const int tmask = (1 << tsh) - 1;

  f32x4 acc[4][2];
#pragma unroll
  for (int i = 0; i < 4; i++)
#pragma unroll
    for (int j = 0; j < 2; j++) acc[i][j] = (f32x4){0.f, 0.f, 0.f, 0.f};

  const TA* Ap[4];
#pragma unroll
  for (int i = 0; i < 4; i++) {
    int r = m0 + i * 16 + lr;
    int arow = ((r >> tsh) << 8) + t0 + (r & tmask);
    Ap[i] = A + (size_t)arow * K + lk;
  }
  const f16* Wp = W + (size_t)(n0 + lr) * K + lk;
  for (int k0 = 0; k0 < K; k0 += 32) {
    f16x8 a[4], b[2];
#pragma unroll
    for (int i = 0; i < 4; i++) a[i] = ld8(Ap[i] + k0);
#pragma unroll
    for (int j = 0; j < 2; j++) b[j] = *(const f16x8*)(Wp + (size_t)(j * 16) * K + k0);
#pragma unroll
    for (int i = 0; i < 4; i++)
#pragma unroll
      for (int j = 0; j < 2; j++)
        acc[i][j] = __builtin_amdgcn_mfma_f32_16x16x32_f16(a[i], b[j], acc[i][j], 0, 0, 0);
  }
  const int rowb = (lane >> 4) * 4;
#pragma unroll
  for (int j = 0; j < 2; j++) {
    int col = n0 + j * 16 + lr;
    float bv = bias[col];
#pragma unroll
    for (int i = 0; i < 4; i++)
#pragma unroll
      for (int r = 0; r < 4; r++) {
        int row = m0 + i * 16 + rowb + r;
        gx[(size_t)row * NG + col] = (f16)(acc[i][j][r] + bv);
      }
  }
}

// ---- GRU recurrence: 64 blocks = 16 groups (16 batch rows) x 4 slices (128 cols).
// Weights register-resident (384 VGPR B-frags/lane). Sibling sync XCD-local when
// the blockIdx%8 round-robin puts the group's 4 blocks on one XCD (verified via
// HW_REG_XCC_ID handshake each launch); else agent-scope + buffer_wbl2 fallback.
__global__ __launch_bounds__(256, 1) void k_rec4(
    const f16* __restrict__ gx, const f16* __restrict__ whh, const float* __restrict__ bhh,
    f16* __restrict__ h, f16* __restrict__ exl, f16* __restrict__ hch, f16* __restrict__ hcl,
    u32* __restrict__ flagsL, u32* __restrict__ xtab, int t0, int Tc) {
  const int tid = threadIdx.x;
  const int w = tid >> 6, lane = tid & 63;
  const int lr = lane & 15, lkh = lane >> 4;
  const int b = blockIdx.x;
  const int s = (b >> 3) & 3;
  const int g = (b & 7) | ((b >> 5) << 3);
  const int base_blk = (g & 7) | ((g >> 3) << 5);
  const int colw = s * 128 + w * 32;

  // one-time: B fragments into registers (issue before handshake barrier)
  f16x8 bf[3][2][16];
#pragma unroll
  for (int ga = 0; ga < 3; ga++)
#pragma unroll
    for (int jt = 0; jt < 2; jt++) {
      const f16* wp = whh + (size_t)(ga * NH + colw + jt * 16 + lr) * NH;
#pragma unroll
      for (int kk = 0; kk < 16; kk++)
        bf[ga][jt][kk] = *(const f16x8*)(wp + kk * 32 + lkh * 8);
    }
  float bh[3][2];
#pragma unroll
  for (int ga = 0; ga < 3; ga++)
#pragma unroll
    for (int jt = 0; jt < 2; jt++) bh[ga][jt] = bhh[ga * NH + colw + jt * 16 + lr];

  // XCD-locality handshake
  __shared__ int s_loc;
  if (tid == 0) {
    u32 xid;
    asm volatile("s_getreg_b32 %0, hwreg(HW_REG_XCC_ID)" : "=s"(xid));
    __hip_atomic_store(&xtab[b], xid + 1u, __ATOMIC_RELAXED, __HIP_MEMORY_SCOPE_AGENT);
    u32 v[4] = {0, 0, 0, 0};
#pragma unroll
    for (int q = 0; q < 4; q++)
      while (!v[q]) {
        v[q] = __hip_atomic_load(&xtab[base_blk + 8 * q], __ATOMIC_RELAXED,
                                 __HIP_MEMORY_SCOPE_AGENT);
        if (!v[q]) __builtin_amdgcn_s_sleep(2);
      }
    s_loc = (v[0] == v[1] && v[1] == v[2] && v[2] == v[3]) ? 1 : 0;
  }
  __syncthreads();
  const bool loc = (s_loc != 0);

  const int tend = t0 + Tc;
  float hold[2][4];
  if (t0 == 0) {
#pragma unroll
    for (int jt = 0; jt < 2; jt++)
#pragma unroll
      for (int r = 0; r < 4; r++) hold[jt][r] = 0.f;
  } else {
#pragma unroll
    for (int jt = 0; jt < 2; jt++)
#pragma unroll
      for (int r = 0; r < 4; r++) {
        size_t ci = (size_t)(g * 16 + lkh * 4 + r) * NH + colw + jt * 16 + lr;
        hold[jt][r] = (float)hch[ci] + (float)hcl[ci];
      }
  }

  u32* fline = flagsL + g * 16;  // 64B line, entries s=0..3

  for (int t = t0; t < tend; t++) {
    // gx for this step (independent of sync -> issue first, hides under poll+MFMA)
    f16 gxv[3][2][4];
    const int tl = t - t0;
#pragma unroll
    for (int r = 0; r < 4; r++) {
      const f16* gp = gx + ((size_t)(g * 16 + lkh * 4 + r) * Tc + tl) * NG + colw + lr;
#pragma unroll
      for (int ga = 0; ga < 3; ga++)
#pragma unroll
        for (int jt = 0; jt < 2; jt++) gxv[ga][jt][r] = gp[ga * NH + jt * 16];
    }
    if (t > t0) {
      const u32 tgt = (u32)t;
      if (loc) {
        const volatile u32x4* fp = (const volatile u32x4*)fline;
        for (;;) {
          u32x4 f = *fp;  // sc0: bypass L1, read shared XCD L2
          u32 m01 = f[0] < f[1] ? f[0] : f[1];
          u32 m23 = f[2] < f[3] ? f[2] : f[3];
          if ((m01 < m23 ? m01 : m23) >= tgt) break;
        }
      } else {
        for (;;) {
          u32 mn = 0xffffffffu;
#pragma unroll
          for (int q = 0; q < 4; q++) {
            u32 f = __hip_atomic_load(fline + q, __ATOMIC_RELAXED, __HIP_MEMORY_SCOPE_AGENT);
            mn = f < mn ? f : mn;
          }
          if (mn >= tgt) break;
          __builtin_amdgcn_s_sleep(1);
        }
      }
    }
    f32x4 acc[3][2];
#pragma unroll
    for (int ga = 0; ga < 3; ga++)
#pragma unroll
      for (int jt = 0; jt < 2; jt++) acc[ga][jt] = (f32x4){0.f, 0.f, 0.f, 0.f};
    if (t > 0) {
      const f16* hip0;
      const f16* lop0;
      if (t == t0) {
        hip0 = hch + (size_t)(g * 16 + lr) * NH;
        lop0 = hcl + (size_t)(g * 16 + lr) * NH;
      } else {
        hip0 = h + ((size_t)(g * 16 + lr) * NT + (t - 1)) * NH;
        lop0 = exl + (size_t)((g * 2 + ((t - 1) & 1)) * 16 + lr) * NH;
      }
      if (loc || t == t0) {
#pragma unroll
        for (int kk = 0; kk < 16; kk++) {
          const int kf = kk * 32 + lkh * 8;
          union { u32x4 q; f16x8 v; } ah, al;
          ah.q = *(const volatile u32x4*)(hip0 + kf);
          al.q = *(const volatile u32x4*)(lop0 + kf);
#pragma unroll
          for (int ga = 0; ga < 3; ga++)
#pragma unroll
            for (int jt = 0; jt < 2; jt++) {
              acc[ga][jt] = __builtin_amdgcn_mfma_f32_16x16x32_f16(ah.v, bf[ga][jt][kk], acc[ga][jt], 0, 0, 0);
              acc[ga][jt] = __builtin_amdgcn_mfma_f32_16x16x32_f16(al.v, bf[ga][jt][kk], acc[ga][jt], 0, 0, 0);
            }
        }
      } else {
#pragma unroll
        for (int kk = 0; kk < 16; kk++) {
          const int kf = kk * 32 + lkh * 8;
          union { u64 q[2]; f16x8 v; } ah, al;
          ah.q[0] = __hip_atomic_load((const u64*)(hip0 + kf), __ATOMIC_RELAXED, __HIP_MEMORY_SCOPE_AGENT);
          ah.q[1] = __hip_atomic_load((const u64*)(hip0 + kf + 4), __ATOMIC_RELAXED, __HIP_MEMORY_SCOPE_AGENT);
          al.q[0] = __hip_atomic_load((const u64*)(lop0 + kf), __ATOMIC_RELAXED, __HIP_MEMORY_SCOPE_AGENT);
          al.q[1] = __hip_atomic_load((const u64*)(lop0 + kf + 4), __ATOMIC_RELAXED, __HIP_MEMORY_SCOPE_AGENT);
#pragma unroll
          for (int ga = 0; ga < 3; ga++)
#pragma unroll
            for (int jt = 0; jt < 2; jt++) {
              acc[ga][jt] = __builtin_amdgcn_mfma_f32_16x16x32_f16(ah.v, bf[ga][jt][kk], acc[ga][jt], 0, 0, 0);
              acc[ga][jt] = __builtin_amdgcn_mfma_f32_16x16x32_f16(al.v, bf[ga][jt][kk], acc[ga][jt], 0, 0, 0);
            }
        }
      }
    }
    // gates + stores
    const int parw = t & 1;
#pragma unroll
    for (int jt = 0; jt < 2; jt++)
#pragma unroll
      for (int r = 0; r < 4; r++) {
        float rg = fsig((float)gxv[0][jt][r] + acc[0][jt][r] + bh[0][jt]);
        float zg = fsig((float)gxv[1][jt][r] + acc[1][jt][r] + bh[1][jt]);
        float hn = acc[2][jt][r] + bh[2][jt];
        float ng = ftanh((float)gxv[2][jt][r] + rg * hn);
        float hnew = ng + zg * (hold[jt][r] - ng);
        hold[jt][r] = hnew;
        f16 hi = (f16)hnew;
        f16 lo = (f16)(hnew - (float)hi);
        const int mrow = lkh * 4 + r;
        const int col = colw + jt * 16 + lr;
        h[((size_t)(g * 16 + mrow) * NT + t) * NH + col] = hi;
        exl[(size_t)((g * 2 + parw) * 16 + mrow) * NH + col] = lo;
        if (t == tend - 1) {
          size_t ci = (size_t)(g * 16 + mrow) * NH + col;
          hch[ci] = hi;
          hcl[ci] = lo;
        }
      }
    if (t < tend - 1) {
      if (loc) {
        asm volatile("s_waitcnt vmcnt(0)" ::: "memory");  // stores in XCD L2
        __syncthreads();
        if (tid == 0)
          __hip_atomic_store(fline + s, (u32)(t + 1), __ATOMIC_RELAXED,
                             __HIP_MEMORY_SCOPE_WORKGROUP);  // plain store, L2-visible
      } else {
        asm volatile("s_waitcnt vmcnt(0)\nbuffer_wbl2\ns_waitcnt vmcnt(0)" ::: "memory");
        __syncthreads();
        if (tid == 0)
          __hip_atomic_store(fline + s, (u32)(t + 1), __ATOMIC_RELAXED,
                             __HIP_MEMORY_SCOPE_AGENT);
      }
    }
  }
}

// ---- final FC
__global__ void k_fc(const f16* __restrict__ h, const float* __restrict__ fcw,
                     const float* __restrict__ fcb, float* __restrict__ out) {
  int b = blockIdx.x;
  int lane = threadIdx.x;  // 64
  __shared__ float hrow[NH];
  for (int k = lane; k < NH; k += 64)
    hrow[k] = (float)h[((size_t)b * NT + (NT - 1)) * NH + k];
  __syncthreads();
  for (int o = 0; o < NOUT; o++) {
    float sm = 0.f;
    for (int k = lane; k < NH; k += 64) sm += hrow[k] * fcw[o * NH + k];
#pragma unroll
    for (int off = 32; off; off >>= 1) sm += __shfl_down(sm, off);
    if (lane == 0) out[b * NOUT + o] = sm + fcb[o];
  }
}

extern "C" void kernel_launch(void* const* d_in, const int* in_sizes, int n_in,
                              void* d_out, int out_size, void* d_ws, size_t ws_size,
                              hipStream_t stream) {
  (void)in_sizes; (void)n_in; (void)out_size;
  const float* x = (const float*)d_in[0];
  const float* w_ih[3] = {(const float*)d_in[1], (const float*)d_in[5], (const float*)d_in[9]};
  const float* w_hh[3] = {(const float*)d_in[2], (const float*)d_in[6], (const float*)d_in[10]};
  const float* b_ih[3] = {(const float*)d_in[3], (const float*)d_in[7], (const float*)d_in[11]};
  const float* b_hh[3] = {(const float*)d_in[4], (const float*)d_in[8], (const float*)d_in[12]};
  const float* fcw = (const float*)d_in[13];
  const float* fcb = (const float*)d_in[14];

  const size_t fixed = 16384 + (size_t)NB * NT * NH * 2 /*h*/ +
                       (size_t)16 * 2 * 16 * NH * 2 /*exl*/ + 6 * (size_t)NB * NH * 2 /*hcar*/ +
                       ((size_t)NG * ND + 2 * (size_t)NG * NH) * 2 /*wih*/ +
                       3 * (size_t)NG * NH * 2 /*whh*/;
  int Tc = 128;
  while (Tc > 16 && fixed + (size_t)NB * Tc * NG * 2 > ws_size) Tc >>= 1;
  const int nc = NT / Tc;
  int tsh = 0;
  while ((1 << tsh) < Tc) tsh++;

  char* p = (char*)d_ws;
  size_t off = 0;
  u32* ctrl = (u32*)(p + off); off += 16384;           // flags(3*256 u32) + xtab(24*64 u32)
  u32* flags = ctrl;                                    // layer l: flags + l*256
  u32* xtab = ctrl + 3 * 256;                           // launch li: xtab + li*64
  f16* wih_f[3]; f16* whh_f[3];
  const int wih_sz[3] = {NG * ND, NG * NH, NG * NH};
  for (int l = 0; l < 3; l++) {
    wih_f[l] = (f16*)(p + off); off += (size_t)wih_sz[l] * 2;
    whh_f[l] = (f16*)(p + off); off += (size_t)NG * NH * 2;
  }
  f16* h = (f16*)(p + off); off += (size_t)NB * NT * NH * 2;
  f16* exl = (f16*)(p + off); off += (size_t)16 * 2 * 16 * NH * 2;
  f16* hch[3]; f16* hcl[3];
  for (int l = 0; l < 3; l++) {
    hch[l] = (f16*)(p + off); off += (size_t)NB * NH * 2;
    hcl[l] = (f16*)(p + off); off += (size_t)NB * NH * 2;
  }
  f16* gx = (f16*)(p + off); off += (size_t)NB * Tc * NG * 2;

  hipMemsetAsync(ctrl, 0, 16384, stream);

  auto conv = [&](const float* src, f16* dst, int n) {
    int blocks = (n + 1023) / 1024; if (blocks > 2048) blocks = 2048;
    k_f32_to_f16<<<dim3(blocks), dim3(256), 0, stream>>>(src, dst, n);
  };
  for (int l = 0; l < 3; l++) {
    conv(w_ih[l], wih_f[l], wih_sz[l]);
    conv(w_hh[l], whh_f[l], NG * NH);
  }

  const int mblocks = (NB * Tc) / 128;
  for (int c = 0; c < nc; c++) {
    const int t0 = c * Tc;
    k_gemm<ND, float><<<dim3(mblocks, 24), dim3(256), 0, stream>>>(x, wih_f[0], b_ih[0], gx, t0, tsh);
    k_rec4<<<dim3(64), dim3(256), 0, stream>>>(gx, whh_f[0], b_hh[0], h, exl, hch[0], hcl[0],
                                               flags + 0 * 256, xtab + (c * 3 + 0) * 64, t0, Tc);
    k_gemm<NH, f16><<<dim3(mblocks, 24), dim3(256), 0, stream>>>(h, wih_f[1], b_ih[1], gx, t0, tsh);
    k_rec4<<<dim3(64), dim3(256), 0, stream>>>(gx, whh_f[1], b_hh[1], h, exl, hch[1], hcl[1],
                                               flags + 1 * 256, xtab + (c * 3 + 1) * 64, t0, Tc);
    k_gemm<NH, f16><<<dim3(mblocks, 24), dim3(256), 0, stream>>>(h, wih_f[2], b_ih[2], gx, t0, tsh);
    k_rec4<<<dim3(64), dim3(256), 0, stream>>>(gx, whh_f[2], b_hh[2], h, exl, hch[2], hcl[2],
                                               flags + 2 * 256, xtab + (c * 3 + 2) * 64, t0, Tc);
  }
  k_fc<<<dim3(NB), dim3(64), 0, stream>>>(h, fcw, fcb, (float*)d_out);
}

// Round 7
// 6420.570 us; speedup vs baseline: 1.6971x; 1.2725x over previous
//
#include <hip/hip_runtime.h>
#include <cstdint>
#include <cstddef>

typedef _Float16 f16;
typedef _Float16 f16x8 __attribute__((ext_vector_type(8)));
typedef float f32x4 __attribute__((ext_vector_type(4)));
typedef unsigned int u32;
typedef u32 u32x4 __attribute__((ext_vector_type(4)));
typedef unsigned long long u64;

#define NB 256
#define NT 256
#define ND 128
#define NH 512
#define NG 1536
#define NOUT 24

__device__ __forceinline__ float fsig(float x) {
  float e = __expf(-x);
  return __fdividef(1.0f, 1.0f + e);
}
__device__ __forceinline__ float ftanh(float x) {
  float ax = __builtin_fabsf(x);
  float e = __expf(-2.0f * ax);
  float t = __fdividef(1.0f - e, 1.0f + e);
  return __builtin_copysignf(t, x);
}

__global__ void k_f32_to_f16(const float* __restrict__ in, f16* __restrict__ out, int n) {
  int stride = gridDim.x * blockDim.x;
  for (int i = blockIdx.x * blockDim.x + threadIdx.x; i < n; i += stride)
    out[i] = (f16)in[i];
}

__device__ __forceinline__ f16x8 ld8(const f16* p) { return *(const f16x8*)p; }
__device__ __forceinline__ f16x8 ld8(const float* p) {
  float4 a = *(const float4*)p;
  float4 b = *(const float4*)(p + 4);
  f16x8 o;
  o[0] = (f16)a.x; o[1] = (f16)a.y; o[2] = (f16)a.z; o[3] = (f16)a.w;
  o[4] = (f16)b.x; o[5] = (f16)b.y; o[6] = (f16)b.z; o[7] = (f16)b.w;
  return o;
}

// ---- gx = A @ W^T + b. M-index r -> batch b=r>>tsh, local t = r&mask.
template <int K, typename TA>
__global__ __launch_bounds__(256) void k_gemm(
    const TA* __restrict__ A, const f16* __restrict__ W,
    const float* __restrict__ bias, f16* __restrict__ gx, int t0, int tsh) {
  const int tid = threadIdx.x;
  const int wave = tid >> 6, lane = tid & 63;
  const int wm = wave >> 1, wn = wave & 1;
  const int m0 = blockIdx.x * 128 + wm * 64;
  const int n0 = blockIdx.y * 64 + wn * 32;
  const int lr = lane & 15;
  const int lk = (lane >> 4) * 8;
  const int tmask = (1 << tsh) - 1;

  f32x4 acc[4][2];
#pragma unroll
  for (int i = 0; i < 4; i++)
#pragma unroll
    for (int j = 0; j < 2; j++) acc[i][j] = (f32x4){0.f, 0.f, 0.f, 0.f};

  const TA* Ap[4];
#pragma unroll
  for (int i = 0; i < 4; i++) {
    int r = m0 + i * 16 + lr;
    int arow = ((r >> tsh) << 8) + t0 + (r & tmask);
    Ap[i] = A + (size_t)arow * K + lk;
  }
  const f16* Wp = W + (size_t)(n0 + lr) * K + lk;
  for (int k0 = 0; k0 < K; k0 += 32) {
    f16x8 a[4], b[2];
#pragma unroll
    for (int i = 0; i < 4; i++) a[i] = ld8(Ap[i] + k0);
#pragma unroll
    for (int j = 0; j < 2; j++) b[j] = *(const f16x8*)(Wp + (size_t)(j * 16) * K + k0);
#pragma unroll
    for (int i = 0; i < 4; i++)
#pragma unroll
      for (int j = 0; j < 2; j++)
        acc[i][j] = __builtin_amdgcn_mfma_f32_16x16x32_f16(a[i], b[j], acc[i][j], 0, 0, 0);
  }
  const int rowb = (lane >> 4) * 4;
#pragma unroll
  for (int j = 0; j < 2; j++) {
    int col = n0 + j * 16 + lr;
    float bv = bias[col];
#pragma unroll
    for (int i = 0; i < 4; i++)
#pragma unroll
      for (int r = 0; r < 4; r++) {
        int row = m0 + i * 16 + rowb + r;
        gx[(size_t)row * NG + col] = (f16)(acc[i][j][r] + bv);
      }
  }
}

// ---- GRU recurrence. 128 blocks = 8 groups (32 batch rows) x 16 slices (32 cols).
// Groups formed DYNAMICALLY per-XCD via HW_REG_XCC_ID roster -> same-XCD sync
// through the shared XCD L2: plain stores + vmcnt, flag poll (agent load),
// buffer_inv (L1 inval) + plain pipelined dwordx4 h loads. Deficient groups
// fall back to agent-scope + buffer_wbl2 (correct cross-XCD).
__global__ __launch_bounds__(256, 1) void k_rec(
    const f16* __restrict__ gx, const f16* __restrict__ whh, const float* __restrict__ bhh,
    f16* __restrict__ h, f16* __restrict__ exl, f16* __restrict__ hch, f16* __restrict__ hcl,
    u32* __restrict__ flagsL, u32* __restrict__ T, int t0, int Tc) {
  __shared__ f16 wlds[96 * 512];
  __shared__ int s_g, s_cs, s_loc;
  const int tid = threadIdx.x;
  const int lane = tid & 63, wave = tid >> 6;
  const int wm = wave >> 1, wn = wave & 1;
  const int lr = lane & 15, lkh = lane >> 4;

  // ---- roster claim ----
  if (tid == 0) {
    u32 xid;
    asm volatile("s_getreg_b32 %0, hwreg(HW_REG_XCC_ID)" : "=s"(xid));
    xid &= 7u;
    u32 slot = __hip_atomic_fetch_add(&T[xid], 1u, __ATOMIC_RELAXED, __HIP_MEMORY_SCOPE_AGENT);
    u32 li = 0u;
    if (slot >= 16u)
      li = __hip_atomic_fetch_add(&T[9], 1u, __ATOMIC_RELAXED, __HIP_MEMORY_SCOPE_AGENT);
    __hip_atomic_fetch_add(&T[8], 1u, __ATOMIC_RELAXED, __HIP_MEMORY_SCOPE_AGENT);
    s_g = (int)xid;
    s_cs = (slot < 16u) ? (int)slot : (int)(16 + li);
  }
  __syncthreads();
  const bool early = (s_cs < 16);
  if (early) {  // stage weights now; overlaps other blocks' registration
    const int c0 = s_cs * 32;
    for (int idx = tid; idx < 96 * 64; idx += 256) {
      int lrw = idx >> 6, c = idx & 63;
      int grow = (lrw >> 5) * NH + c0 + (lrw & 31);
      f16x8 v = *(const f16x8*)(whh + (size_t)grow * NH + c * 8);
      *(f16x8*)(wlds + lrw * 512 + ((c ^ (lrw & 7)) << 3)) = v;
    }
  }
  if (tid == 0) {
    while (__hip_atomic_load(&T[8], __ATOMIC_RELAXED, __HIP_MEMORY_SCOPE_AGENT) < 128u)
      __builtin_amdgcn_s_sleep(4);
    u32 c[8];
#pragma unroll
    for (int q = 0; q < 8; q++) {
      u32 cc = __hip_atomic_load(&T[q], __ATOMIC_RELAXED, __HIP_MEMORY_SCOPE_AGENT);
      c[q] = cc < 16u ? cc : 16u;
    }
    if (s_cs < 16) {
      s_loc = (c[s_g] >= 16u) ? 1 : 0;
    } else {
      int li = s_cs - 16, idx = 0, fg = 0, fs = 0;
      for (int x2 = 0; x2 < 8; x2++)
        for (int s2 = (int)c[x2]; s2 < 16; s2++) {
          if (idx == li) { fg = x2; fs = s2; }
          idx++;
        }
      s_g = fg; s_cs = fs; s_loc = 0;
    }
  }
  __syncthreads();
  if (!early) {
    const int c0 = s_cs * 32;
    for (int idx = tid; idx < 96 * 64; idx += 256) {
      int lrw = idx >> 6, c = idx & 63;
      int grow = (lrw >> 5) * NH + c0 + (lrw & 31);
      f16x8 v = *(const f16x8*)(whh + (size_t)grow * NH + c * 8);
      *(f16x8*)(wlds + lrw * 512 + ((c ^ (lrw & 7)) << 3)) = v;
    }
    __syncthreads();
  }
  const int g = s_g, cs = s_cs;
  const bool loc = (s_loc != 0);

  const int jloc = wn * 16 + lr;
  const int j = cs * 32 + jloc;
  const float bh_r = bhh[j], bh_z = bhh[NH + j], bh_n = bhh[2 * NH + j];
  const int arow = g * 32 + wm * 16 + lr;          // A-fragment row (global batch row)
  const int lrow = wm * 16 + lr;                   // local row for exl
  const int rowbase = g * 32 + wm * 16 + lkh * 4;  // C rows base
  const int swz = jloc & 7;
  const f16* wr_ = wlds + jloc * 512;
  const f16* wz_ = wlds + (32 + jloc) * 512;
  const f16* wn_ = wlds + (64 + jloc) * 512;
  u32* fline = flagsL + g * 16;

  union H8 { u32x4 q; u64 d[2]; f16x8 v; };

  const int tend = t0 + Tc;
  float hold[4];
  if (t0 == 0) {
#pragma unroll
    for (int r = 0; r < 4; r++) hold[r] = 0.f;
  } else {
#pragma unroll
    for (int r = 0; r < 4; r++) {
      size_t ci = (size_t)(rowbase + r) * NH + j;
      hold[r] = (float)hch[ci] + (float)hcl[ci];
    }
  }

  // prefetch gx for first step
  float xr[4], xz[4], xn[4];
#pragma unroll
  for (int r = 0; r < 4; r++) {
    const f16* gp = gx + ((size_t)(rowbase + r) * Tc) * NG + j;
    xr[r] = (float)gp[0]; xz[r] = (float)gp[NH]; xn[r] = (float)gp[2 * NH];
  }

  for (int t = t0; t < tend; t++) {
    if (t > t0) {
      const u32 tgt = (u32)t;
      if (loc) {
        for (;;) {
          u32 v = __hip_atomic_load(fline + (lane & 15), __ATOMIC_RELAXED,
                                    __HIP_MEMORY_SCOPE_AGENT);
          if (__all(v >= tgt)) break;
        }
        asm volatile("buffer_inv" ::: "memory");  // drop L1; h data is in XCD L2
      } else {
        for (;;) {
          u32 v = __hip_atomic_load(fline + (lane & 15), __ATOMIC_RELAXED,
                                    __HIP_MEMORY_SCOPE_AGENT);
          if (__all(v >= tgt)) break;
          __builtin_amdgcn_s_sleep(1);
        }
        asm volatile("" ::: "memory");
      }
    }
    f32x4 ar = {0.f, 0.f, 0.f, 0.f}, az = {0.f, 0.f, 0.f, 0.f}, an = {0.f, 0.f, 0.f, 0.f};
    if (t > 0) {
      const f16* hip0;
      const f16* lop0;
      if (t == t0) {
        hip0 = hch + (size_t)arow * NH;
        lop0 = hcl + (size_t)arow * NH;
      } else {
        hip0 = h + ((size_t)arow * NT + (t - 1)) * NH;
        lop0 = exl + (size_t)((g * 2 + ((t - 1) & 1)) * 32 + lrow) * NH;
      }
      if (loc || t == t0) {
#pragma unroll
        for (int kk = 0; kk < 16; kk++) {
          const int kf = kk * 32 + lkh * 8;
          H8 ah, al;
          ah.q = *(const u32x4*)(hip0 + kf);   // plain, pipelined, L2-hit
          al.q = *(const u32x4*)(lop0 + kf);
          const int co = (((kk * 4 + lkh) ^ swz) << 3);
          f16x8 br = *(const f16x8*)(wr_ + co);
          f16x8 bz = *(const f16x8*)(wz_ + co);
          f16x8 bn = *(const f16x8*)(wn_ + co);
          ar = __builtin_amdgcn_mfma_f32_16x16x32_f16(ah.v, br, ar, 0, 0, 0);
          az = __builtin_amdgcn_mfma_f32_16x16x32_f16(ah.v, bz, az, 0, 0, 0);
          an = __builtin_amdgcn_mfma_f32_16x16x32_f16(ah.v, bn, an, 0, 0, 0);
          ar = __builtin_amdgcn_mfma_f32_16x16x32_f16(al.v, br, ar, 0, 0, 0);
          az = __builtin_amdgcn_mfma_f32_16x16x32_f16(al.v, bz, az, 0, 0, 0);
          an = __builtin_amdgcn_mfma_f32_16x16x32_f16(al.v, bn, an, 0, 0, 0);
        }
      } else {
#pragma unroll
        for (int kk = 0; kk < 16; kk++) {
          const int kf = kk * 32 + lkh * 8;
          H8 ah, al;
          ah.d[0] = __hip_atomic_load((const u64*)(hip0 + kf), __ATOMIC_RELAXED, __HIP_MEMORY_SCOPE_AGENT);
          ah.d[1] = __hip_atomic_load((const u64*)(hip0 + kf + 4), __ATOMIC_RELAXED, __HIP_MEMORY_SCOPE_AGENT);
          al.d[0] = __hip_atomic_load((const u64*)(lop0 + kf), __ATOMIC_RELAXED, __HIP_MEMORY_SCOPE_AGENT);
          al.d[1] = __hip_atomic_load((const u64*)(lop0 + kf + 4), __ATOMIC_RELAXED, __HIP_MEMORY_SCOPE_AGENT);
          const int co = (((kk * 4 + lkh) ^ swz) << 3);
          f16x8 br = *(const f16x8*)(wr_ + co);
          f16x8 bz = *(const f16x8*)(wz_ + co);
          f16x8 bn = *(const f16x8*)(wn_ + co);
          ar = __builtin_amdgcn_mfma_f32_16x16x32_f16(ah.v, br, ar, 0, 0, 0);
          az = __builtin_amdgcn_mfma_f32_16x16x32_f16(ah.v, bz, az, 0, 0, 0);
          an = __builtin_amdgcn_mfma_f32_16x16x32_f16(ah.v, bn, an, 0, 0, 0);
          ar = __builtin_amdgcn_mfma_f32_16x16x32_f16(al.v, br, ar, 0, 0, 0);
          az = __builtin_amdgcn_mfma_f32_16x16x32_f16(al.v, bz, az, 0, 0, 0);
          an = __builtin_amdgcn_mfma_f32_16x16x32_f16(al.v, bn, an, 0, 0, 0);
        }
      }
    }
    // gates + stores
    const int parw = t & 1;
#pragma unroll
    for (int r = 0; r < 4; r++) {
      float rg = fsig(xr[r] + ar[r] + bh_r);
      float zg = fsig(xz[r] + az[r] + bh_z);
      float ng = ftanh(xn[r] + rg * (an[r] + bh_n));
      float hnew = ng + zg * (hold[r] - ng);
      hold[r] = hnew;
      f16 hi = (f16)hnew;
      f16 lo = (f16)(hnew - (float)hi);
      const int grow = rowbase + r;
      h[((size_t)grow * NT + t) * NH + j] = hi;
      exl[(size_t)((g * 2 + parw) * 32 + (wm * 16 + lkh * 4 + r)) * NH + j] = lo;
      if (t == tend - 1) {
        size_t ci = (size_t)grow * NH + j;
        hch[ci] = hi;
        hcl[ci] = lo;
      }
    }
    if (t < tend - 1) {
      if (loc) {
        asm volatile("s_waitcnt vmcnt(0)" ::: "memory");  // stores in XCD L2
        __syncthreads();
        if (tid == 0)
          __hip_atomic_store(fline + cs, (u32)(t + 1), __ATOMIC_RELAXED,
                             __HIP_MEMORY_SCOPE_WORKGROUP);
      } else {
        asm volatile("s_waitcnt vmcnt(0)\nbuffer_wbl2\ns_waitcnt vmcnt(0)" ::: "memory");
        __syncthreads();
        if (tid == 0)
          __hip_atomic_store(fline + cs, (u32)(t + 1), __ATOMIC_RELAXED,
                             __HIP_MEMORY_SCOPE_AGENT);
      }
      // prefetch next step's gx (hidden under the next poll)
#pragma unroll
      for (int r = 0; r < 4; r++) {
        const f16* gp = gx + ((size_t)(rowbase + r) * Tc + (t + 1 - t0)) * NG + j;
        xr[r] = (float)gp[0]; xz[r] = (float)gp[NH]; xn[r] = (float)gp[2 * NH];
      }
      asm volatile("" ::: "memory");
    }
  }
}

// ---- final FC
__global__ void k_fc(const f16* __restrict__ h, const float* __restrict__ fcw,
                     const float* __restrict__ fcb, float* __restrict__ out) {
  int b = blockIdx.x;
  int lane = threadIdx.x;  // 64
  __shared__ float hrow[NH];
  for (int k = lane; k < NH; k += 64)
    hrow[k] = (float)h[((size_t)b * NT + (NT - 1)) * NH + k];
  __syncthreads();
  for (int o = 0; o < NOUT; o++) {
    float sm = 0.f;
    for (int k = lane; k < NH; k += 64) sm += hrow[k] * fcw[o * NH + k];
#pragma unroll
    for (int off = 32; off; off >>= 1) sm += __shfl_down(sm, off);
    if (lane == 0) out[b * NOUT + o] = sm + fcb[o];
  }
}

extern "C" void kernel_launch(void* const* d_in, const int* in_sizes, int n_in,
                              void* d_out, int out_size, void* d_ws, size_t ws_size,
                              hipStream_t stream) {
  (void)in_sizes; (void)n_in; (void)out_size;
  const float* x = (const float*)d_in[0];
  const float* w_ih[3] = {(const float*)d_in[1], (const float*)d_in[5], (const float*)d_in[9]};
  const float* w_hh[3] = {(const float*)d_in[2], (const float*)d_in[6], (const float*)d_in[10]};
  const float* b_ih[3] = {(const float*)d_in[3], (const float*)d_in[7], (const float*)d_in[11]};
  const float* b_hh[3] = {(const float*)d_in[4], (const float*)d_in[8], (const float*)d_in[12]};
  const float* fcw = (const float*)d_in[13];
  const float* fcb = (const float*)d_in[14];

  const size_t fixed = 32768 + ((size_t)NG * ND + 2 * (size_t)NG * NH) * 2 +
                       3 * (size_t)NG * NH * 2 + (size_t)NB * NT * NH * 2 +
                       (size_t)8 * 2 * 32 * NH * 2 + 6 * (size_t)NB * NH * 2;
  int Tc = 128;
  while (Tc > 16 && fixed + (size_t)NB * Tc * NG * 2 > ws_size) Tc >>= 1;
  const int nc = NT / Tc;
  int tsh = 0;
  while ((1 << tsh) < Tc) tsh++;

  char* p = (char*)d_ws;
  size_t off = 0;
  u32* ctrl = (u32*)(p + off); off += 32768;
  u32* flags = ctrl;                 // layer l: flags + l*128 (8 groups x 16)
  u32* xtab = ctrl + 512;            // launch li: xtab + li*16 (8 ctr + total + leftover)
  f16* wih_f[3]; f16* whh_f[3];
  const int wih_sz[3] = {NG * ND, NG * NH, NG * NH};
  for (int l = 0; l < 3; l++) {
    wih_f[l] = (f16*)(p + off); off += (size_t)wih_sz[l] * 2;
    whh_f[l] = (f16*)(p + off); off += (size_t)NG * NH * 2;
  }
  f16* h = (f16*)(p + off); off += (size_t)NB * NT * NH * 2;
  f16* exl = (f16*)(p + off); off += (size_t)8 * 2 * 32 * NH * 2;
  f16* hch[3]; f16* hcl[3];
  for (int l = 0; l < 3; l++) {
    hch[l] = (f16*)(p + off); off += (size_t)NB * NH * 2;
    hcl[l] = (f16*)(p + off); off += (size_t)NB * NH * 2;
  }
  f16* gx = (f16*)(p + off); off += (size_t)NB * Tc * NG * 2;

  hipMemsetAsync(ctrl, 0, 32768, stream);

  auto conv = [&](const float* src, f16* dst, int n) {
    int blocks = (n + 1023) / 1024; if (blocks > 2048) blocks = 2048;
    k_f32_to_f16<<<dim3(blocks), dim3(256), 0, stream>>>(src, dst, n);
  };
  for (int l = 0; l < 3; l++) {
    conv(w_ih[l], wih_f[l], wih_sz[l]);
    conv(w_hh[l], whh_f[l], NG * NH);
  }

  const int mblocks = (NB * Tc) / 128;
  int li = 0;
  for (int c = 0; c < nc; c++) {
    const int t0 = c * Tc;
    k_gemm<ND, float><<<dim3(mblocks, 24), dim3(256), 0, stream>>>(x, wih_f[0], b_ih[0], gx, t0, tsh);
    k_rec<<<dim3(128), dim3(256), 0, stream>>>(gx, whh_f[0], b_hh[0], h, exl, hch[0], hcl[0],
                                               flags + 0 * 128, xtab + (li++) * 16, t0, Tc);
    k_gemm<NH, f16><<<dim3(mblocks, 24), dim3(256), 0, stream>>>(h, wih_f[1], b_ih[1], gx, t0, tsh);
    k_rec<<<dim3(128), dim3(256), 0, stream>>>(gx, whh_f[1], b_hh[1], h, exl, hch[1], hcl[1],
                                               flags + 1 * 128, xtab + (li++) * 16, t0, Tc);
    k_gemm<NH, f16><<<dim3(mblocks, 24), dim3(256), 0, stream>>>(h, wih_f[2], b_ih[2], gx, t0, tsh);
    k_rec<<<dim3(128), dim3(256), 0, stream>>>(gx, whh_f[2], b_hh[2], h, exl, hch[2], hcl[2],
                                               flags + 2 * 128, xtab + (li++) * 16, t0, Tc);
  }
  k_fc<<<dim3(NB), dim3(64), 0, stream>>>(h, fcw, fcb, (float*)d_out);
}

// Round 9
// 5877.255 us; speedup vs baseline: 1.8540x; 1.0924x over previous
//
#include <hip/hip_runtime.h>
#include <cstdint>
#include <cstddef>

typedef _Float16 f16;
typedef _Float16 f16x8 __attribute__((ext_vector_type(8)));
typedef float f32x4 __attribute__((ext_vector_type(4)));
typedef unsigned int u32;
typedef u32 u32x4 __attribute__((ext_vector_type(4)));

#define NB 256
#define NT 256
#define ND 128
#define NH 512
#define NG 1536
#define NOUT 24
#define GROUPS 8
#define SLICES 16

__device__ __forceinline__ float fsig(float x) {
  float e = __expf(-x);
  return __fdividef(1.0f, 1.0f + e);
}
__device__ __forceinline__ float ftanh(float x) {
  float ax = __builtin_fabsf(x);
  float e = __expf(-2.0f * ax);
  float t = __fdividef(1.0f - e, 1.0f + e);
  return __builtin_copysignf(t, x);
}

__global__ void k_f32_to_f16(const float* __restrict__ in, f16* __restrict__ out, int n) {
  int stride = gridDim.x * blockDim.x;
  for (int i = blockIdx.x * blockDim.x + threadIdx.x; i < n; i += stride)
    out[i] = (f16)in[i];
}

__device__ __forceinline__ f16x8 ld8(const f16* p) { return *(const f16x8*)p; }
__device__ __forceinline__ f16x8 ld8(const float* p) {
  float4 a = *(const float4*)p;
  float4 b = *(const float4*)(p + 4);
  f16x8 o;
  o[0] = (f16)a.x; o[1] = (f16)a.y; o[2] = (f16)a.z; o[3] = (f16)a.w;
  o[4] = (f16)b.x; o[5] = (f16)b.y; o[6] = (f16)b.z; o[7] = (f16)b.w;
  return o;
}

// ---- gx = A @ W^T + b. M-index r -> batch b=r>>tsh, local t = r&mask. (r7, proven)
template <int K, typename TA>
__global__ __launch_bounds__(256) void k_gemm(
    const TA* __restrict__ A, const f16* __restrict__ W,
    const float* __restrict__ bias, f16* __restrict__ gx, int t0, int tsh) {
  const int tid = threadIdx.x;
  const int wave = tid >> 6, lane = tid & 63;
  const int wm = wave >> 1, wn = wave & 1;
  const int m0 = blockIdx.x * 128 + wm * 64;
  const int n0 = blockIdx.y * 64 + wn * 32;
  const int lr = lane & 15;
  const int lk = (lane >> 4) * 8;
  const int tmask = (1 << tsh) - 1;

  f32x4 acc[4][2];
#pragma unroll
  for (int i = 0; i < 4; i++)
#pragma unroll
    for (int jj = 0; jj < 2; jj++) acc[i][jj] = (f32x4){0.f, 0.f, 0.f, 0.f};

  const TA* Ap[4];
#pragma unroll
  for (int i = 0; i < 4; i++) {
    int r = m0 + i * 16 + lr;
    int arow = ((r >> tsh) << 8) + t0 + (r & tmask);
    Ap[i] = A + (size_t)arow * K + lk;
  }
  const f16* Wp = W + (size_t)(n0 + lr) * K + lk;
  for (int k0 = 0; k0 < K; k0 += 32) {
    f16x8 a[4], b[2];
#pragma unroll
    for (int i = 0; i < 4; i++) a[i] = ld8(Ap[i] + k0);
#pragma unroll
    for (int jj = 0; jj < 2; jj++) b[jj] = *(const f16x8*)(Wp + (size_t)(jj * 16) * K + k0);
#pragma unroll
    for (int i = 0; i < 4; i++)
#pragma unroll
      for (int jj = 0; jj < 2; jj++)
        acc[i][jj] = __builtin_amdgcn_mfma_f32_16x16x32_f16(a[i], b[jj], acc[i][jj], 0, 0, 0);
  }
  const int rowb = (lane >> 4) * 4;
#pragma unroll
  for (int jj = 0; jj < 2; jj++) {
    int col = n0 + jj * 16 + lr;
    float bv = bias[col];
#pragma unroll
    for (int i = 0; i < 4; i++)
#pragma unroll
      for (int r = 0; r < 4; r++) {
        int row = m0 + i * 16 + rowb + r;
        gx[(size_t)row * NG + col] = (f16)(acc[i][jj][r] + bv);
      }
  }
}

// issue one batch of 4 kk (8 dwordx4 system-scope loads)
#define ISSUE4(qarr, kkb)                                                      \
  _Pragma("unroll") for (int u_ = 0; u_ < 4; u_++) {                           \
    const u32* pp_ = hq + (kkb + u_) * 32 + lkh * 8;                           \
    asm volatile("global_load_dwordx4 %0, %1, off sc0 sc1"                     \
                 : "=v"(qarr[2 * u_]) : "v"(pp_));                             \
    asm volatile("global_load_dwordx4 %0, %1, off sc0 sc1"                     \
                 : "=v"(qarr[2 * u_ + 1]) : "v"(pp_ + 4));                     \
  }

// consume one batch: unpack packed(hi|lo) u32 -> f16x8 hi/lo planes, 6 MFMA per kk
#define CONSUME4(qarr, kkb)                                                    \
  _Pragma("unroll") for (int u_ = 0; u_ < 4; u_++) {                           \
    const int kk_ = kkb + u_;                                                  \
    u32 p_[8];                                                                 \
    _Pragma("unroll") for (int i2 = 0; i2 < 4; i2++) {                         \
      p_[i2] = qarr[2 * u_][i2];                                               \
      p_[4 + i2] = qarr[2 * u_ + 1][i2];                                       \
    }                                                                          \
    union { u32 w[4]; f16x8 v; } AH_, AL_;                                     \
    _Pragma("unroll") for (int i2 = 0; i2 < 4; i2++) {                         \
      AH_.w[i2] = __builtin_amdgcn_perm(p_[2 * i2 + 1], p_[2 * i2], 0x05040100u); \
      AL_.w[i2] = __builtin_amdgcn_perm(p_[2 * i2 + 1], p_[2 * i2], 0x07060302u); \
    }                                                                          \
    const int co_ = (((kk_ * 4 + lkh) ^ swz) << 3);                            \
    f16x8 br_ = *(const f16x8*)(wr_ + co_);                                    \
    f16x8 bz_ = *(const f16x8*)(wz_ + co_);                                    \
    f16x8 bn_ = *(const f16x8*)(wn_ + co_);                                    \
    ar = __builtin_amdgcn_mfma_f32_16x16x32_f16(AH_.v, br_, ar, 0, 0, 0);      \
    az = __builtin_amdgcn_mfma_f32_16x16x32_f16(AH_.v, bz_, az, 0, 0, 0);      \
    an = __builtin_amdgcn_mfma_f32_16x16x32_f16(AH_.v, bn_, an, 0, 0, 0);      \
    ar = __builtin_amdgcn_mfma_f32_16x16x32_f16(AL_.v, br_, ar, 0, 0, 0);      \
    az = __builtin_amdgcn_mfma_f32_16x16x32_f16(AL_.v, bz_, az, 0, 0, 0);      \
    an = __builtin_amdgcn_mfma_f32_16x16x32_f16(AL_.v, bn_, an, 0, 0, 0);      \
  }

// ---- GRU recurrence over one time chunk. 128 blocks = 8 groups x 16 slices,
// 256 thr. Agent-scope (MALL) exchange, packed hi|lo u32 plane, BATCHED
// pipelined dwordx4 loads (sliding vmcnt(8) window). Flag-line barrier.
__global__ __launch_bounds__(256, 1) void k_rec(
    const f16* __restrict__ gx, const f16* __restrict__ whh, const float* __restrict__ bhh,
    f16* __restrict__ h, u32* __restrict__ exq, u32* __restrict__ fl,
    int t0, int Tc, int bar_base) {
  __shared__ f16 wlds[96 * 512];
  const int tid = threadIdx.x;
  const int g = blockIdx.x >> 4;
  const int cs = blockIdx.x & 15;
  const int b0 = g * 32, c0 = cs * 32;
  const int lane = tid & 63, wave = tid >> 6;
  const int wm = wave >> 1, wn = wave & 1;
  const int lr = lane & 15, lkh = lane >> 4;
  const int first = (t0 == 0) ? 1 : 0;

  for (int idx = tid; idx < 96 * 64; idx += 256) {
    int lrw = idx >> 6, c = idx & 63;
    int grow = (lrw >> 5) * NH + c0 + (lrw & 31);
    f16x8 v = *(const f16x8*)(whh + (size_t)grow * NH + c * 8);
    *(f16x8*)(wlds + lrw * 512 + ((c ^ (lrw & 7)) << 3)) = v;
  }
  __syncthreads();

  const int jloc = wn * 16 + lr;
  const int j = c0 + jloc;
  const float bh_r = bhh[j], bh_z = bhh[NH + j], bh_n = bhh[2 * NH + j];
  const int arow = b0 + wm * 16 + lr;
  const int rowbase = b0 + wm * 16 + lkh * 4;
  const int swz = jloc & 7;
  const f16* wr_ = wlds + jloc * 512;
  const f16* wz_ = wlds + (32 + jloc) * 512;
  const f16* wn_ = wlds + (64 + jloc) * 512;
  u32* myflag = fl + ((g * 16 + cs) << 4);
  u32* gflags = fl + ((g * 16) << 4);
  const int pl = lane & 15;

  union PK2 { u32 u; f16 hh[2]; };

  float hold[4];
  if (first) {
#pragma unroll
    for (int r = 0; r < 4; r++) hold[r] = 0.f;
  } else {
#pragma unroll
    for (int r = 0; r < 4; r++) {
      PK2 pk;
      pk.u = __hip_atomic_load(exq + (size_t)(rowbase + r) * NH + j,
                               __ATOMIC_RELAXED, __HIP_MEMORY_SCOPE_AGENT);
      hold[r] = (float)pk.hh[0] + (float)pk.hh[1];
    }
  }

  // gx prefetch for t=0
  float xr[4], xz[4], xn[4];
#pragma unroll
  for (int r = 0; r < 4; r++) {
    const f16* gp = gx + ((size_t)(rowbase + r) * Tc) * NG + j;
    xr[r] = (float)gp[0]; xz[r] = (float)gp[NH]; xn[r] = (float)gp[2 * NH];
  }

  int cur = 0;
  for (int t = 0; t < Tc; t++) {
    f32x4 ar = {0.f, 0.f, 0.f, 0.f}, az = {0.f, 0.f, 0.f, 0.f}, an = {0.f, 0.f, 0.f, 0.f};
    if (t > 0 || !first) {
      const u32* hq = exq + (size_t)cur * (NB * NH) + (size_t)arow * NH;
      u32x4 q0[8], q1[8];
      ISSUE4(q0, 0);
      ISSUE4(q1, 4);
      asm volatile("s_waitcnt vmcnt(8)" ::: "memory");
      __builtin_amdgcn_sched_barrier(0);
      CONSUME4(q0, 0);
      ISSUE4(q0, 8);
      asm volatile("s_waitcnt vmcnt(8)" ::: "memory");
      __builtin_amdgcn_sched_barrier(0);
      CONSUME4(q1, 4);
      ISSUE4(q1, 12);
      asm volatile("s_waitcnt vmcnt(8)" ::: "memory");
      __builtin_amdgcn_sched_barrier(0);
      CONSUME4(q0, 8);
      asm volatile("s_waitcnt vmcnt(0)" ::: "memory");
      __builtin_amdgcn_sched_barrier(0);
      CONSUME4(q1, 12);
    }
    u32* outq = exq + (size_t)(cur ^ 1) * (NB * NH);
    f16 hhi_s[4];
#pragma unroll
    for (int r = 0; r < 4; r++) {
      float rg = fsig(xr[r] + ar[r] + bh_r);
      float zg = fsig(xz[r] + az[r] + bh_z);
      float ng = ftanh(xn[r] + rg * (an[r] + bh_n));
      float hnew = ng + zg * (hold[r] - ng);
      hold[r] = hnew;
      PK2 pk;
      pk.hh[0] = (f16)hnew;
      pk.hh[1] = (f16)(hnew - (float)pk.hh[0]);
      hhi_s[r] = pk.hh[0];
      __hip_atomic_store(outq + (size_t)(rowbase + r) * NH + j, pk.u,
                         __ATOMIC_RELAXED, __HIP_MEMORY_SCOPE_AGENT);
    }
    if (t < Tc - 1) {
      asm volatile("s_waitcnt vmcnt(0)" ::: "memory");  // exchange stores at MALL
      __syncthreads();
      if (tid == 0)
        __hip_atomic_store(myflag, (u32)(bar_base + t + 1),
                           __ATOMIC_RELAXED, __HIP_MEMORY_SCOPE_AGENT);
      // hout + next gx prefetch hidden under the poll
#pragma unroll
      for (int r = 0; r < 4; r++)
        h[((size_t)(rowbase + r) * NT + (t0 + t)) * NH + j] = hhi_s[r];
#pragma unroll
      for (int r = 0; r < 4; r++) {
        const f16* gp = gx + ((size_t)(rowbase + r) * Tc + (t + 1)) * NG + j;
        xr[r] = (float)gp[0]; xz[r] = (float)gp[NH]; xn[r] = (float)gp[2 * NH];
      }
      asm volatile("" ::: "memory");
      const u32 target = (u32)(bar_base + t + 1);
      for (;;) {
        u32 v = __hip_atomic_load(gflags + (pl << 4),
                                  __ATOMIC_RELAXED, __HIP_MEMORY_SCOPE_AGENT);
        if (__all(v >= target)) break;
        __builtin_amdgcn_s_sleep(1);
      }
      asm volatile("" ::: "memory");
    } else {
#pragma unroll
      for (int r = 0; r < 4; r++)
        h[((size_t)(rowbase + r) * NT + (t0 + t)) * NH + j] = hhi_s[r];
    }
    cur ^= 1;
  }
}

// ---- final FC
__global__ void k_fc(const f16* __restrict__ h, const float* __restrict__ fcw,
                     const float* __restrict__ fcb, float* __restrict__ out) {
  int b = blockIdx.x;
  int lane = threadIdx.x;  // 64
  __shared__ float hrow[NH];
  for (int k = lane; k < NH; k += 64)
    hrow[k] = (float)h[((size_t)b * NT + (NT - 1)) * NH + k];
  __syncthreads();
  for (int o = 0; o < NOUT; o++) {
    float sm = 0.f;
    for (int k = lane; k < NH; k += 64) sm += hrow[k] * fcw[o * NH + k];
#pragma unroll
    for (int off = 32; off; off >>= 1) sm += __shfl_down(sm, off);
    if (lane == 0) out[b * NOUT + o] = sm + fcb[o];
  }
}

extern "C" void kernel_launch(void* const* d_in, const int* in_sizes, int n_in,
                              void* d_out, int out_size, void* d_ws, size_t ws_size,
                              hipStream_t stream) {
  (void)in_sizes; (void)n_in; (void)out_size;
  const float* x = (const float*)d_in[0];
  const float* w_ih[3] = {(const float*)d_in[1], (const float*)d_in[5], (const float*)d_in[9]};
  const float* w_hh[3] = {(const float*)d_in[2], (const float*)d_in[6], (const float*)d_in[10]};
  const float* b_ih[3] = {(const float*)d_in[3], (const float*)d_in[7], (const float*)d_in[11]};
  const float* b_hh[3] = {(const float*)d_in[4], (const float*)d_in[8], (const float*)d_in[12]};
  const float* fcw = (const float*)d_in[13];
  const float* fcb = (const float*)d_in[14];

  const size_t fixed = 32768 +
                       ((size_t)NG * ND + 2 * (size_t)NG * NH) * 2 /*wih*/ +
                       3 * (size_t)NG * NH * 2 /*whh*/ +
                       (size_t)NB * NT * NH * 2 /*h*/ +
                       3 * (size_t)2 * NB * NH * 4 /*exq*/;
  int Tc = 128;
  while (Tc > 16 && fixed + (size_t)NB * Tc * NG * 2 > ws_size) Tc >>= 1;
  const int nc = NT / Tc;
  int tsh = 0;
  while ((1 << tsh) < Tc) tsh++;

  char* p = (char*)d_ws;
  size_t off = 0;
  u32* ctrl = (u32*)(p + off); off += 32768;  // 3 layers x 8 groups x 16 lines x 64B
  f16* wih_f[3]; f16* whh_f[3];
  const int wih_sz[3] = {NG * ND, NG * NH, NG * NH};
  for (int l = 0; l < 3; l++) {
    wih_f[l] = (f16*)(p + off); off += (size_t)wih_sz[l] * 2;
    whh_f[l] = (f16*)(p + off); off += (size_t)NG * NH * 2;
  }
  f16* h = (f16*)(p + off); off += (size_t)NB * NT * NH * 2;
  u32* exq[3];
  for (int l = 0; l < 3; l++) {
    exq[l] = (u32*)(p + off); off += (size_t)2 * NB * NH * 4;
  }
  f16* gx = (f16*)(p + off); off += (size_t)NB * Tc * NG * 2;

  hipMemsetAsync(ctrl, 0, 32768, stream);

  auto conv = [&](const float* src, f16* dst, int n) {
    int blocks = (n + 1023) / 1024; if (blocks > 2048) blocks = 2048;
    k_f32_to_f16<<<dim3(blocks), dim3(256), 0, stream>>>(src, dst, n);
  };
  for (int l = 0; l < 3; l++) {
    conv(w_ih[l], wih_f[l], wih_sz[l]);
    conv(w_hh[l], whh_f[l], NG * NH);
  }

  const int mblocks = (NB * Tc) / 128;
  for (int c = 0; c < nc; c++) {
    const int t0 = c * Tc;
    const int bar_base = c * (Tc - 1);
    k_gemm<ND, float><<<dim3(mblocks, 24), dim3(256), 0, stream>>>(x, wih_f[0], b_ih[0], gx, t0, tsh);
    k_rec<<<dim3(GROUPS * SLICES), dim3(256), 0, stream>>>(
        gx, whh_f[0], b_hh[0], h, exq[0], ctrl + 0 * 2048, t0, Tc, bar_base);
    k_gemm<NH, f16><<<dim3(mblocks, 24), dim3(256), 0, stream>>>(h, wih_f[1], b_ih[1], gx, t0, tsh);
    k_rec<<<dim3(GROUPS * SLICES), dim3(256), 0, stream>>>(
        gx, whh_f[1], b_hh[1], h, exq[1], ctrl + 1 * 2048, t0, Tc, bar_base);
    k_gemm<NH, f16><<<dim3(mblocks, 24), dim3(256), 0, stream>>>(h, wih_f[2], b_ih[2], gx, t0, tsh);
    k_rec<<<dim3(GROUPS * SLICES), dim3(256), 0, stream>>>(
        gx, whh_f[2], b_hh[2], h, exq[2], ctrl + 2 * 2048, t0, Tc, bar_base);
  }
  k_fc<<<dim3(NB), dim3(64), 0, stream>>>(h, fcw, fcb, (float*)d_out);
}